// Round 1
// baseline (1932.092 us; speedup 1.0000x reference)
//
#include <hip/hip_runtime.h>

#define NN 50000
#define NE 1600000
#define ET (NE + NN)   // edges + self loops = 1,650,000
#define H1 8
#define C1 16
#define D1 128         // H1*C1
#define C2 16

static inline int cdiv_ll(long long a, int b) { return (int)((a + b - 1) / b); }

// ---------------- layer 1 GEMM: Y[N,128] = X[N,128] @ W[128,128] ----------------
__global__ void gemm_xw1_k(const float* __restrict__ X, const float* __restrict__ W,
                           float* __restrict__ Y) {
  __shared__ float Ws[D1 * D1];              // exactly 64 KB
  for (int i = threadIdx.x; i < D1 * D1; i += blockDim.x) Ws[i] = W[i];
  __syncthreads();
  const int sub = threadIdx.x >> 7;          // 0..1 (2 rows per block-iter)
  const int col = threadIdx.x & 127;
  for (int row = blockIdx.x * 2 + sub; row < NN; row += gridDim.x * 2) {
    const float* xr = X + (size_t)row * D1;
    float acc = 0.f;
#pragma unroll
    for (int k = 0; k < D1; ++k) acc = fmaf(xr[k], Ws[k * D1 + col], acc);
    Y[(size_t)row * D1 + col] = acc;
  }
}

// ---------------- per-(node,head) attention logits ----------------
__global__ void alpha1_k(const float* __restrict__ h1, const float* __restrict__ a_s,
                         const float* __restrict__ a_d, float* __restrict__ s_out,
                         float* __restrict__ d_out_) {
  int idx = blockIdx.x * blockDim.x + threadIdx.x;   // n*H1 + h
  if (idx >= NN * H1) return;
  int h = idx & (H1 - 1);
  const float* hp = h1 + (size_t)idx * C1;           // n*128 + h*16 == idx*16
  const float* ps = a_s + h * C1;
  const float* pd = a_d + h * C1;
  float s = 0.f, d = 0.f;
#pragma unroll
  for (int c = 0; c < C1; ++c) { float v = hp[c]; s = fmaf(v, ps[c], s); d = fmaf(v, pd[c], d); }
  s_out[idx] = s;
  d_out_[idx] = d;
}

// ---------------- softmax denominators, layer 1 (8 heads) ----------------
__global__ void edge_denom1_k(const int* __restrict__ ei, const float* __restrict__ as,
                              const float* __restrict__ ad, float* __restrict__ den) {
  int e = blockIdx.x * blockDim.x + threadIdx.x;
  if (e >= ET) return;
  int s, d;
  if (e < NE) { s = ei[e]; d = ei[NE + e]; } else { s = d = e - NE; }
#pragma unroll
  for (int h = 0; h < H1; ++h) {
    float ev = as[s * H1 + h] + ad[d * H1 + h];
    ev = ev > 0.f ? ev : 0.2f * ev;
    atomicAdd(&den[d * H1 + h], __expf(ev));
  }
}

__global__ void recip_k(float* __restrict__ p, int n) {
  int i = blockIdx.x * blockDim.x + threadIdx.x;
  if (i < n) p[i] = 1.f / p[i];
}

// ---------------- aggregate layer 1: 128 threads per edge ----------------
__global__ void edge_agg1_k(const int* __restrict__ ei, const float* __restrict__ h1,
                            const float* __restrict__ as, const float* __restrict__ ad,
                            const float* __restrict__ rden, float* __restrict__ outp) {
  long long gid = (long long)blockIdx.x * blockDim.x + threadIdx.x;
  if (gid >= (long long)ET * D1) return;
  int ch = (int)(gid & 127);
  int e  = (int)(gid >> 7);
  int s, d;
  if (e < NE) { s = ei[e]; d = ei[NE + e]; } else { s = d = e - NE; }
  int h = ch >> 4;
  float ev = as[s * H1 + h] + ad[d * H1 + h];
  ev = ev > 0.f ? ev : 0.2f * ev;
  float w = __expf(ev) * rden[d * H1 + h];
  atomicAdd(&outp[(size_t)d * D1 + ch], h1[(size_t)s * D1 + ch] * w);
}

// ---------------- bias + ELU in place ----------------
__global__ void bias_elu_k(float* __restrict__ z, const float* __restrict__ b) {
  int i = blockIdx.x * blockDim.x + threadIdx.x;
  if (i >= NN * D1) return;
  float v = z[i] + b[i & 127];
  z[i] = v > 0.f ? v : __expf(v) - 1.f;
}

// ---------------- layer 2 GEMM: h2[N,16] = Z[N,128] @ W2[128,16] ----------------
__global__ void gemm2_k(const float* __restrict__ Z, const float* __restrict__ W,
                        float* __restrict__ Y) {
  __shared__ float Ws[D1 * C2];      // 8 KB
  __shared__ float Zs[16][D1];       // 8 KB
  for (int i = threadIdx.x; i < D1 * C2; i += 256) Ws[i] = W[i];
  int rb = blockIdx.x * 16;
  for (int i = threadIdx.x; i < 16 * D1; i += 256) {
    int r = i >> 7, c = i & 127;
    Zs[r][c] = Z[(size_t)(rb + r) * D1 + c];
  }
  __syncthreads();
  int r = threadIdx.x >> 4, c = threadIdx.x & 15;
  float acc = 0.f;
#pragma unroll
  for (int k = 0; k < D1; ++k) acc = fmaf(Zs[r][k], Ws[k * C2 + c], acc);
  Y[(size_t)(rb + r) * C2 + c] = acc;
}

// ---------------- layer 2 attention logits (1 head) ----------------
__global__ void alpha2_k(const float* __restrict__ h2, const float* __restrict__ a_s,
                         const float* __restrict__ a_d, float* __restrict__ s_out,
                         float* __restrict__ d_out_) {
  int n = blockIdx.x * blockDim.x + threadIdx.x;
  if (n >= NN) return;
  float s = 0.f, d = 0.f;
#pragma unroll
  for (int c = 0; c < C2; ++c) { float v = h2[n * C2 + c]; s = fmaf(v, a_s[c], s); d = fmaf(v, a_d[c], d); }
  s_out[n] = s;
  d_out_[n] = d;
}

__global__ void edge_denom2_k(const int* __restrict__ ei, const float* __restrict__ as,
                              const float* __restrict__ ad, float* __restrict__ den) {
  int e = blockIdx.x * blockDim.x + threadIdx.x;
  if (e >= ET) return;
  int s, d;
  if (e < NE) { s = ei[e]; d = ei[NE + e]; } else { s = d = e - NE; }
  float ev = as[s] + ad[d];
  ev = ev > 0.f ? ev : 0.2f * ev;
  atomicAdd(&den[d], __expf(ev));
}

// ---------------- aggregate layer 2: 16 threads per edge ----------------
__global__ void edge_agg2_k(const int* __restrict__ ei, const float* __restrict__ h2,
                            const float* __restrict__ as, const float* __restrict__ ad,
                            const float* __restrict__ rden, float* __restrict__ outp) {
  long long gid = (long long)blockIdx.x * blockDim.x + threadIdx.x;
  if (gid >= (long long)ET * C2) return;
  int ch = (int)(gid & 15);
  int e  = (int)(gid >> 4);
  int s, d;
  if (e < NE) { s = ei[e]; d = ei[NE + e]; } else { s = d = e - NE; }
  float ev = as[s] + ad[d];
  ev = ev > 0.f ? ev : 0.2f * ev;
  float w = __expf(ev) * rden[d];
  atomicAdd(&outp[(size_t)d * C2 + ch], h2[(size_t)s * C2 + ch] * w);
}

__global__ void bias2_k(float* __restrict__ outp, const float* __restrict__ b) {
  int i = blockIdx.x * blockDim.x + threadIdx.x;
  if (i >= NN * C2) return;
  outp[i] += b[i & 15];
}

extern "C" void kernel_launch(void* const* d_in, const int* in_sizes, int n_in,
                              void* d_out, int out_size, void* d_ws, size_t ws_size,
                              hipStream_t stream) {
  const float* x    = (const float*)d_in[0];
  const int*   ei   = (const int*)d_in[1];
  const float* W1   = (const float*)d_in[2];
  const float* aS1  = (const float*)d_in[3];
  const float* aD1  = (const float*)d_in[4];
  const float* b1   = (const float*)d_in[5];
  const float* W2   = (const float*)d_in[6];
  const float* aS2  = (const float*)d_in[7];
  const float* aD2  = (const float*)d_in[8];
  const float* b2   = (const float*)d_in[9];
  float* outp = (float*)d_out;

  float* ws = (float*)d_ws;
  float* h1   = ws; ws += (size_t)NN * D1;   // 6.4M f
  float* agg1 = ws; ws += (size_t)NN * D1;   // 6.4M f (becomes z after bias+ELU)
  float* as1  = ws; ws += NN * H1;
  float* ad1  = ws; ws += NN * H1;
  float* den1 = ws; ws += NN * H1;
  float* h2   = ws; ws += NN * C2;
  float* as2  = ws; ws += NN;
  float* ad2  = ws; ws += NN;
  float* den2 = ws; ws += NN;

  hipMemsetAsync(agg1, 0, (size_t)NN * D1 * sizeof(float), stream);
  hipMemsetAsync(den1, 0, (size_t)NN * H1 * sizeof(float), stream);
  hipMemsetAsync(den2, 0, (size_t)NN * sizeof(float), stream);
  hipMemsetAsync(outp, 0, (size_t)NN * C2 * sizeof(float), stream);

  gemm_xw1_k<<<1024, 256, 0, stream>>>(x, W1, h1);
  alpha1_k<<<cdiv_ll((long long)NN * H1, 256), 256, 0, stream>>>(h1, aS1, aD1, as1, ad1);
  edge_denom1_k<<<cdiv_ll(ET, 256), 256, 0, stream>>>(ei, as1, ad1, den1);
  recip_k<<<cdiv_ll((long long)NN * H1, 256), 256, 0, stream>>>(den1, NN * H1);
  edge_agg1_k<<<cdiv_ll((long long)ET * D1, 256), 256, 0, stream>>>(ei, h1, as1, ad1, den1, agg1);
  bias_elu_k<<<cdiv_ll((long long)NN * D1, 256), 256, 0, stream>>>(agg1, b1);
  gemm2_k<<<NN / 16, 256, 0, stream>>>(agg1, W2, h2);
  alpha2_k<<<cdiv_ll(NN, 256), 256, 0, stream>>>(h2, aS2, aD2, as2, ad2);
  edge_denom2_k<<<cdiv_ll(ET, 256), 256, 0, stream>>>(ei, as2, ad2, den2);
  recip_k<<<cdiv_ll(NN, 256), 256, 0, stream>>>(den2, NN);
  edge_agg2_k<<<cdiv_ll((long long)ET * C2, 256), 256, 0, stream>>>(ei, h2, as2, ad2, den2, outp);
  bias2_k<<<cdiv_ll((long long)NN * C2, 256), 256, 0, stream>>>(outp, b2);
}

// Round 2
// 716.055 us; speedup vs baseline: 2.6982x; 2.6982x over previous
//
#include <hip/hip_runtime.h>

#define NN 50000
#define NE 1600000
#define ET (NE + NN)   // 1,650,000 incl. self loops
#define H1 8
#define C1 16
#define D1 128
#define C2 16
#define NB1 196        // ceil(NN/256)

static inline int cdiv_ll(long long a, int b) { return (int)((a + b - 1) / b); }

// ============ CSR build ============
__global__ void hist_k(const int* __restrict__ ei, int* __restrict__ hist) {
  int e = blockIdx.x * blockDim.x + threadIdx.x;
  if (e >= ET) return;
  int d = (e < NE) ? ei[NE + e] : (e - NE);
  atomicAdd(&hist[d], 1);
}

// per-256-chunk inclusive scan
__global__ void scan1_k(const int* __restrict__ hist, int* __restrict__ incl,
                        int* __restrict__ bsum) {
  __shared__ int sm[256];
  int t = threadIdx.x, i = blockIdx.x * 256 + t;
  int v = (i < NN) ? hist[i] : 0;
  sm[t] = v; __syncthreads();
  for (int off = 1; off < 256; off <<= 1) {
    int u = (t >= off) ? sm[t - off] : 0;
    __syncthreads();
    sm[t] += u;
    __syncthreads();
  }
  if (i < NN) incl[i] = sm[t];
  if (t == 255) bsum[blockIdx.x] = sm[255];
}

__global__ void scan2_k(const int* __restrict__ bsum, int* __restrict__ boff) {
  __shared__ int sm[256];
  int t = threadIdx.x;
  int v = (t < NB1) ? bsum[t] : 0;
  sm[t] = v; __syncthreads();
  for (int off = 1; off < 256; off <<= 1) {
    int u = (t >= off) ? sm[t - off] : 0;
    __syncthreads();
    sm[t] += u;
    __syncthreads();
  }
  if (t < NB1) boff[t] = sm[t] - v;   // exclusive
}

__global__ void scan3_k(const int* __restrict__ hist, const int* __restrict__ incl,
                        const int* __restrict__ boff, int* __restrict__ rowptr,
                        int* __restrict__ cursor) {
  int i = blockIdx.x * 256 + threadIdx.x;
  if (i >= NN) return;
  int r = incl[i] - hist[i] + boff[i >> 8];   // exclusive scan
  rowptr[i] = r;
  cursor[i] = r;
  if (i == 0) rowptr[NN] = ET;
}

__global__ void scatter_k(const int* __restrict__ ei, int* __restrict__ cursor,
                          unsigned short* __restrict__ srcs) {
  int e = blockIdx.x * blockDim.x + threadIdx.x;
  if (e >= ET) return;
  int s, d;
  if (e < NE) { s = ei[e]; d = ei[NE + e]; } else { s = d = e - NE; }
  int pos = atomicAdd(&cursor[d], 1);
  srcs[pos] = (unsigned short)s;
}

// ============ layer 1 GEMM: h1 = X @ W1 ============
__global__ void gemm_xw1_k(const float* __restrict__ X, const float* __restrict__ W,
                           float* __restrict__ Y) {
  __shared__ float Ws[D1 * D1];
  for (int i = threadIdx.x; i < D1 * D1; i += blockDim.x) Ws[i] = W[i];
  __syncthreads();
  const int sub = threadIdx.x >> 7;
  const int col = threadIdx.x & 127;
  for (int row = blockIdx.x * 2 + sub; row < NN; row += gridDim.x * 2) {
    const float* xr = X + (size_t)row * D1;
    float acc = 0.f;
#pragma unroll
    for (int k = 0; k < D1; ++k) acc = fmaf(xr[k], Ws[k * D1 + col], acc);
    Y[(size_t)row * D1 + col] = acc;
  }
}

// ============ attention logits, layer 1 ============
__global__ void alpha1_k(const float* __restrict__ h1, const float* __restrict__ a_s,
                         const float* __restrict__ a_d, float* __restrict__ s_out,
                         float* __restrict__ d_out_) {
  int idx = blockIdx.x * blockDim.x + threadIdx.x;   // n*H1 + h
  if (idx >= NN * H1) return;
  int h = idx & (H1 - 1);
  const float* hp = h1 + (size_t)idx * C1;
  const float* ps = a_s + h * C1;
  const float* pd = a_d + h * C1;
  float s = 0.f, d = 0.f;
#pragma unroll
  for (int c = 0; c < C1; ++c) { float v = hp[c]; s = fmaf(v, ps[c], s); d = fmaf(v, pd[c], d); }
  s_out[idx] = s;
  d_out_[idx] = d;
}

// ============ fused layer-1 aggregation: one block (128 thr) per dst ============
__global__ void agg1_fused_k(const int* __restrict__ rowptr, const unsigned short* __restrict__ srcs,
                             const float* __restrict__ h1, const float* __restrict__ as,
                             const float* __restrict__ ad, const float* __restrict__ b,
                             float* __restrict__ z) {
  __shared__ int ssrc[128];
  const int d = blockIdx.x;
  const int ch = threadIdx.x;
  const int h = ch >> 4;
  const int beg = rowptr[d], end = rowptr[d + 1];
  const float add = ad[d * H1 + h];
  float acc = 0.f, den = 0.f;
  for (int base = beg; base < end; base += 128) {
    int m = min(128, end - base);
    if (ch < m) ssrc[ch] = (int)srcs[base + ch];
    __syncthreads();
    for (int j = 0; j < m; ++j) {
      int s = ssrc[j];
      float e = as[s * H1 + h] + add;
      e = e > 0.f ? e : 0.2f * e;
      float w = __expf(e);
      den += w;
      acc = fmaf(w, h1[(size_t)s * D1 + ch], acc);
    }
    __syncthreads();
  }
  float v = acc / den + b[ch];
  z[(size_t)d * D1 + ch] = v > 0.f ? v : __expf(v) - 1.f;
}

// ============ layer 2 GEMM: h2 = Z @ W2 ============
__global__ void gemm2_k(const float* __restrict__ Z, const float* __restrict__ W,
                        float* __restrict__ Y) {
  __shared__ float Ws[D1 * C2];
  __shared__ float Zs[16][D1];
  for (int i = threadIdx.x; i < D1 * C2; i += 256) Ws[i] = W[i];
  int rb = blockIdx.x * 16;
  for (int i = threadIdx.x; i < 16 * D1; i += 256) {
    int r = i >> 7, c = i & 127;
    Zs[r][c] = Z[(size_t)(rb + r) * D1 + c];
  }
  __syncthreads();
  int r = threadIdx.x >> 4, c = threadIdx.x & 15;
  float acc = 0.f;
#pragma unroll
  for (int k = 0; k < D1; ++k) acc = fmaf(Zs[r][k], Ws[k * C2 + c], acc);
  Y[(size_t)(rb + r) * C2 + c] = acc;
}

// ============ attention logits, layer 2 ============
__global__ void alpha2_k(const float* __restrict__ h2, const float* __restrict__ a_s,
                         const float* __restrict__ a_d, float* __restrict__ s_out,
                         float* __restrict__ d_out_) {
  int n = blockIdx.x * blockDim.x + threadIdx.x;
  if (n >= NN) return;
  float s = 0.f, d = 0.f;
#pragma unroll
  for (int c = 0; c < C2; ++c) { float v = h2[n * C2 + c]; s = fmaf(v, a_s[c], s); d = fmaf(v, a_d[c], d); }
  s_out[n] = s;
  d_out_[n] = d;
}

// ============ fused layer-2 aggregation: 16 threads per dst, 16 dst per block ============
__global__ void agg2_fused_k(const int* __restrict__ rowptr, const unsigned short* __restrict__ srcs,
                             const float* __restrict__ h2, const float* __restrict__ as,
                             const float* __restrict__ ad, const float* __restrict__ b,
                             float* __restrict__ outp) {
  const int d = blockIdx.x * 16 + (threadIdx.x >> 4);
  const int ch = threadIdx.x & 15;
  const int beg = rowptr[d], end = rowptr[d + 1];
  const float add = ad[d];
  float acc = 0.f, den = 0.f;
  for (int j = beg; j < end; ++j) {
    int s = (int)srcs[j];
    float e = as[s] + add;
    e = e > 0.f ? e : 0.2f * e;
    float w = __expf(e);
    den += w;
    acc = fmaf(w, h2[(size_t)s * C2 + ch], acc);
  }
  outp[(size_t)d * C2 + ch] = acc / den + b[ch];
}

extern "C" void kernel_launch(void* const* d_in, const int* in_sizes, int n_in,
                              void* d_out, int out_size, void* d_ws, size_t ws_size,
                              hipStream_t stream) {
  const float* x    = (const float*)d_in[0];
  const int*   ei   = (const int*)d_in[1];
  const float* W1   = (const float*)d_in[2];
  const float* aS1  = (const float*)d_in[3];
  const float* aD1  = (const float*)d_in[4];
  const float* b1   = (const float*)d_in[5];
  const float* W2   = (const float*)d_in[6];
  const float* aS2  = (const float*)d_in[7];
  const float* aD2  = (const float*)d_in[8];
  const float* b2   = (const float*)d_in[9];
  float* outp = (float*)d_out;

  // ---- workspace layout ----
  char* p = (char*)d_ws;
  float* h1   = (float*)p; p += (size_t)NN * D1 * 4;     // 25.6 MB
  float* z    = (float*)p; p += (size_t)NN * D1 * 4;     // 25.6 MB
  float* as1  = (float*)p; p += (size_t)NN * H1 * 4;
  float* ad1  = (float*)p; p += (size_t)NN * H1 * 4;
  int*   hist   = (int*)p; p += (size_t)NN * 4;
  int*   incl   = (int*)p; p += (size_t)NN * 4;
  int*   rowptr = (int*)p; p += (size_t)(NN + 1) * 4;
  int*   cursor = (int*)p; p += (size_t)NN * 4;
  int*   bsum   = (int*)p; p += 256 * 4;
  int*   boff   = (int*)p; p += 256 * 4;
  unsigned short* srcs = (unsigned short*)p; p += (size_t)ET * 2;
  // layer-2 tensors alias h1 (dead after agg1)
  float* h2  = h1;                       // NN*C2
  float* as2 = h1 + (size_t)NN * C2;     // NN
  float* ad2 = as2 + NN;                 // NN

  hipMemsetAsync(hist, 0, (size_t)NN * 4, stream);

  // CSR build (graph is static per call but ws is re-poisoned, so rebuild)
  hist_k   <<<cdiv_ll(ET, 256), 256, 0, stream>>>(ei, hist);
  scan1_k  <<<NB1, 256, 0, stream>>>(hist, incl, bsum);
  scan2_k  <<<1, 256, 0, stream>>>(bsum, boff);
  scan3_k  <<<NB1, 256, 0, stream>>>(hist, incl, boff, rowptr, cursor);
  scatter_k<<<cdiv_ll(ET, 256), 256, 0, stream>>>(ei, cursor, srcs);

  // layer 1
  gemm_xw1_k  <<<1024, 256, 0, stream>>>(x, W1, h1);
  alpha1_k    <<<cdiv_ll((long long)NN * H1, 256), 256, 0, stream>>>(h1, aS1, aD1, as1, ad1);
  agg1_fused_k<<<NN, 128, 0, stream>>>(rowptr, srcs, h1, as1, ad1, b1, z);

  // layer 2
  gemm2_k     <<<NN / 16, 256, 0, stream>>>(z, W2, h2);
  alpha2_k    <<<cdiv_ll(NN, 256), 256, 0, stream>>>(h2, aS2, aD2, as2, ad2);
  agg2_fused_k<<<NN / 16, 256, 0, stream>>>(rowptr, srcs, h2, as2, ad2, b2, outp);
}

// Round 3
// 456.516 us; speedup vs baseline: 4.2323x; 1.5685x over previous
//
#include <hip/hip_runtime.h>

#define NN 50000
#define NE 1600000
#define ET (NE + NN)   // 1,650,000 incl. self loops
#define H1 8
#define C1 16
#define D1 128
#define C2 16
#define NB1 196        // ceil(NN/256)

static inline int cdiv_ll(long long a, int b) { return (int)((a + b - 1) / b); }

// ============ CSR build ============
__global__ __launch_bounds__(256) void hist_k(const int* __restrict__ ei, int* __restrict__ hist) {
  int e = blockIdx.x * blockDim.x + threadIdx.x;
  if (e >= ET) return;
  int d = (e < NE) ? ei[NE + e] : (e - NE);
  atomicAdd(&hist[d], 1);
}

__global__ __launch_bounds__(256) void scan1_k(const int* __restrict__ hist, int* __restrict__ incl,
                                               int* __restrict__ bsum) {
  __shared__ int sm[256];
  int t = threadIdx.x, i = blockIdx.x * 256 + t;
  int v = (i < NN) ? hist[i] : 0;
  sm[t] = v; __syncthreads();
  for (int off = 1; off < 256; off <<= 1) {
    int u = (t >= off) ? sm[t - off] : 0;
    __syncthreads();
    sm[t] += u;
    __syncthreads();
  }
  if (i < NN) incl[i] = sm[t];
  if (t == 255) bsum[blockIdx.x] = sm[255];
}

__global__ __launch_bounds__(256) void scan2_k(const int* __restrict__ bsum, int* __restrict__ boff) {
  __shared__ int sm[256];
  int t = threadIdx.x;
  int v = (t < NB1) ? bsum[t] : 0;
  sm[t] = v; __syncthreads();
  for (int off = 1; off < 256; off <<= 1) {
    int u = (t >= off) ? sm[t - off] : 0;
    __syncthreads();
    sm[t] += u;
    __syncthreads();
  }
  if (t < NB1) boff[t] = sm[t] - v;   // exclusive
}

__global__ __launch_bounds__(256) void scan3_k(const int* __restrict__ hist, const int* __restrict__ incl,
                                               const int* __restrict__ boff, int* __restrict__ rowptr,
                                               int* __restrict__ cursor) {
  int i = blockIdx.x * 256 + threadIdx.x;
  if (i >= NN) return;
  int r = incl[i] - hist[i] + boff[i >> 8];   // exclusive scan
  rowptr[i] = r;
  cursor[i] = r;
  if (i == 0) rowptr[NN] = ET;
}

__global__ __launch_bounds__(256) void scatter_k(const int* __restrict__ ei, int* __restrict__ cursor,
                                                 unsigned short* __restrict__ srcs) {
  int e = blockIdx.x * blockDim.x + threadIdx.x;
  if (e >= ET) return;
  int s, d;
  if (e < NE) { s = ei[e]; d = ei[NE + e]; } else { s = d = e - NE; }
  int pos = atomicAdd(&cursor[d], 1);
  srcs[pos] = (unsigned short)s;
}

// ============ layer 1 GEMM + fused alpha1 ============
// 64 rows x 128 cols per block; 256 threads; 8x4 register blocking.
__global__ __launch_bounds__(256) void gemm1_k(const float* __restrict__ X,
    const float* __restrict__ W, const float* __restrict__ aS,
    const float* __restrict__ aD, float* __restrict__ Y,
    float* __restrict__ as1, float* __restrict__ ad1) {
  __shared__ float Xs[32][68];    // [k][row], pad 68 (16B-aligned rows, conflict-light stores)
  __shared__ float Wt[32][128];   // [k][col]
  const int tid = threadIdx.x;
  const int tx = tid & 31;        // cols tx*4 .. tx*4+3
  const int ty = tid >> 5;        // rows ty*8 .. ty*8+7
  const int row0 = blockIdx.x * 64;
  float acc[8][4] = {};

  for (int kt = 0; kt < D1; kt += 32) {
    {
      int r = tid >> 3, c4 = tid & 7;
#pragma unroll
      for (int it = 0; it < 2; ++it) {
        int row = r + it * 32;
        int grow = row0 + row; if (grow > NN - 1) grow = NN - 1;
        float4 v = *(const float4*)(X + (size_t)grow * D1 + kt + c4 * 4);
        Xs[c4 * 4 + 0][row] = v.x; Xs[c4 * 4 + 1][row] = v.y;
        Xs[c4 * 4 + 2][row] = v.z; Xs[c4 * 4 + 3][row] = v.w;
      }
    }
#pragma unroll
    for (int it = 0; it < 4; ++it) {
      int idx = it * 256 + tid;
      int kk = idx >> 5, cc = (idx & 31) * 4;
      *(float4*)&Wt[kk][cc] = *(const float4*)(W + (size_t)(kt + kk) * D1 + cc);
    }
    __syncthreads();
#pragma unroll
    for (int k = 0; k < 32; ++k) {
      float4 w4 = *(const float4*)&Wt[k][tx * 4];
      float4 xa = *(const float4*)&Xs[k][ty * 8];
      float4 xb = *(const float4*)&Xs[k][ty * 8 + 4];
      float xv[8] = {xa.x, xa.y, xa.z, xa.w, xb.x, xb.y, xb.z, xb.w};
      float wv[4] = {w4.x, w4.y, w4.z, w4.w};
#pragma unroll
      for (int rr = 0; rr < 8; ++rr)
#pragma unroll
        for (int cc = 0; cc < 4; ++cc)
          acc[rr][cc] = fmaf(xv[rr], wv[cc], acc[rr][cc]);
    }
    __syncthreads();
  }

  // epilogue: store Y row-slices + fused per-(row,head) attention logits
  const int h = tx >> 2;           // this thread's 4 cols live in head h
  const int cin = (tx * 4) & 15;   // col-within-head
  float a_sv[4], a_dv[4];
#pragma unroll
  for (int j = 0; j < 4; ++j) { a_sv[j] = aS[h * 16 + cin + j]; a_dv[j] = aD[h * 16 + cin + j]; }
#pragma unroll
  for (int rr = 0; rr < 8; ++rr) {
    int grow = row0 + ty * 8 + rr;
    if (grow < NN) {   // uniform within each 4-lane shuffle group
      float4 o = {acc[rr][0], acc[rr][1], acc[rr][2], acc[rr][3]};
      *(float4*)(Y + (size_t)grow * D1 + tx * 4) = o;
      float ps = acc[rr][0] * a_sv[0] + acc[rr][1] * a_sv[1] + acc[rr][2] * a_sv[2] + acc[rr][3] * a_sv[3];
      float pd = acc[rr][0] * a_dv[0] + acc[rr][1] * a_dv[1] + acc[rr][2] * a_dv[2] + acc[rr][3] * a_dv[3];
      ps += __shfl_xor(ps, 1); pd += __shfl_xor(pd, 1);
      ps += __shfl_xor(ps, 2); pd += __shfl_xor(pd, 2);
      if ((tx & 3) == 0) { as1[grow * H1 + h] = ps; ad1[grow * H1 + h] = pd; }
    }
  }
}

// ============ fused layer-1 aggregation: one block (128 thr) per dst ============
__global__ __launch_bounds__(128) void agg1_k(const int* __restrict__ rowptr,
    const unsigned short* __restrict__ srcs, const float* __restrict__ h1,
    const float* __restrict__ as, const float* __restrict__ ad,
    const float* __restrict__ b, float* __restrict__ z) {
  __shared__ int ssrc[128];
  const int d = blockIdx.x;
  const int ch = threadIdx.x;
  const int h = ch >> 4;
  const int beg = rowptr[d], end = rowptr[d + 1];
  const float add = ad[(size_t)d * H1 + h];
  float acc0 = 0, acc1 = 0, acc2 = 0, acc3 = 0;
  float den0 = 0, den1 = 0, den2 = 0, den3 = 0;
  for (int base = beg; base < end; base += 128) {
    int m = min(128, end - base);
    if (ch < m) ssrc[ch] = (int)srcs[base + ch];
    __syncthreads();
    int j = 0;
    for (; j + 4 <= m; j += 4) {
      int s0 = ssrc[j], s1 = ssrc[j + 1], s2 = ssrc[j + 2], s3 = ssrc[j + 3];
      float e0 = as[s0 * H1 + h] + add, e1 = as[s1 * H1 + h] + add;
      float e2 = as[s2 * H1 + h] + add, e3 = as[s3 * H1 + h] + add;
      e0 = e0 > 0.f ? e0 : 0.2f * e0; e1 = e1 > 0.f ? e1 : 0.2f * e1;
      e2 = e2 > 0.f ? e2 : 0.2f * e2; e3 = e3 > 0.f ? e3 : 0.2f * e3;
      float w0 = __expf(e0), w1 = __expf(e1), w2 = __expf(e2), w3 = __expf(e3);
      den0 += w0; den1 += w1; den2 += w2; den3 += w3;
      acc0 = fmaf(w0, h1[(size_t)s0 * D1 + ch], acc0);
      acc1 = fmaf(w1, h1[(size_t)s1 * D1 + ch], acc1);
      acc2 = fmaf(w2, h1[(size_t)s2 * D1 + ch], acc2);
      acc3 = fmaf(w3, h1[(size_t)s3 * D1 + ch], acc3);
    }
    for (; j < m; ++j) {
      int s0 = ssrc[j];
      float e0 = as[s0 * H1 + h] + add;
      e0 = e0 > 0.f ? e0 : 0.2f * e0;
      float w0 = __expf(e0);
      den0 += w0;
      acc0 = fmaf(w0, h1[(size_t)s0 * D1 + ch], acc0);
    }
    __syncthreads();
  }
  float den = (den0 + den1) + (den2 + den3);
  float acc = (acc0 + acc1) + (acc2 + acc3);
  float v = acc / den + b[ch];
  z[(size_t)d * D1 + ch] = v > 0.f ? v : __expf(v) - 1.f;
}

// ============ layer 2 GEMM + fused alpha2 ============
__global__ __launch_bounds__(256) void gemm2_k(const float* __restrict__ Z,
    const float* __restrict__ W, const float* __restrict__ aS,
    const float* __restrict__ aD, float* __restrict__ Y,
    float* __restrict__ as2, float* __restrict__ ad2) {
  __shared__ float Ws[D1][C2];        // 8 KB
  __shared__ float Zs[16][D1 + 4];    // pad 132 -> 2-way (free) bank access
  const int tid = threadIdx.x;
  for (int i = tid; i < D1 * C2; i += 256) Ws[i >> 4][i & 15] = W[i];
  const int rb = blockIdx.x * 16;
  {
    int r = tid >> 5, c4 = (tid & 31) * 4;
#pragma unroll
    for (int it = 0; it < 2; ++it) {
      int rr = r + it * 8;
      float4 v = *(const float4*)(Z + (size_t)(rb + rr) * D1 + c4);
      *(float4*)&Zs[rr][c4] = v;
    }
  }
  __syncthreads();
  const int r = tid >> 4, c = tid & 15;
  float a0 = 0, a1 = 0, a2 = 0, a3 = 0;
#pragma unroll
  for (int k = 0; k < D1; k += 4) {
    float4 z4 = *(const float4*)&Zs[r][k];
    a0 = fmaf(z4.x, Ws[k][c], a0);
    a1 = fmaf(z4.y, Ws[k + 1][c], a1);
    a2 = fmaf(z4.z, Ws[k + 2][c], a2);
    a3 = fmaf(z4.w, Ws[k + 3][c], a3);
  }
  float acc = (a0 + a1) + (a2 + a3);
  Y[(size_t)(rb + r) * C2 + c] = acc;
  float ps = acc * aS[c], pd = acc * aD[c];
  ps += __shfl_xor(ps, 1); pd += __shfl_xor(pd, 1);
  ps += __shfl_xor(ps, 2); pd += __shfl_xor(pd, 2);
  ps += __shfl_xor(ps, 4); pd += __shfl_xor(pd, 4);
  ps += __shfl_xor(ps, 8); pd += __shfl_xor(pd, 8);
  if (c == 0) { as2[rb + r] = ps; ad2[rb + r] = pd; }
}

// ============ fused layer-2 aggregation: 16 threads per dst ============
__global__ __launch_bounds__(256) void agg2_k(const int* __restrict__ rowptr,
    const unsigned short* __restrict__ srcs, const float* __restrict__ h2,
    const float* __restrict__ as, const float* __restrict__ ad,
    const float* __restrict__ b, float* __restrict__ outp) {
  const int d = blockIdx.x * 16 + (threadIdx.x >> 4);
  const int ch = threadIdx.x & 15;
  const int beg = rowptr[d], end = rowptr[d + 1];
  const float add = ad[d];
  float acc0 = 0, acc1 = 0, acc2 = 0, acc3 = 0;
  float den0 = 0, den1 = 0, den2 = 0, den3 = 0;
  int j = beg;
  for (; j + 4 <= end; j += 4) {
    int s0 = srcs[j], s1 = srcs[j + 1], s2 = srcs[j + 2], s3 = srcs[j + 3];
    float e0 = as[s0] + add, e1 = as[s1] + add, e2 = as[s2] + add, e3 = as[s3] + add;
    e0 = e0 > 0.f ? e0 : 0.2f * e0; e1 = e1 > 0.f ? e1 : 0.2f * e1;
    e2 = e2 > 0.f ? e2 : 0.2f * e2; e3 = e3 > 0.f ? e3 : 0.2f * e3;
    float w0 = __expf(e0), w1 = __expf(e1), w2 = __expf(e2), w3 = __expf(e3);
    den0 += w0; den1 += w1; den2 += w2; den3 += w3;
    acc0 = fmaf(w0, h2[(size_t)s0 * C2 + ch], acc0);
    acc1 = fmaf(w1, h2[(size_t)s1 * C2 + ch], acc1);
    acc2 = fmaf(w2, h2[(size_t)s2 * C2 + ch], acc2);
    acc3 = fmaf(w3, h2[(size_t)s3 * C2 + ch], acc3);
  }
  for (; j < end; ++j) {
    int s0 = srcs[j];
    float e0 = as[s0] + add;
    e0 = e0 > 0.f ? e0 : 0.2f * e0;
    float w0 = __expf(e0);
    den0 += w0;
    acc0 = fmaf(w0, h2[(size_t)s0 * C2 + ch], acc0);
  }
  outp[(size_t)d * C2 + ch] = ((acc0 + acc1) + (acc2 + acc3)) / ((den0 + den1) + (den2 + den3)) + b[ch];
}

extern "C" void kernel_launch(void* const* d_in, const int* in_sizes, int n_in,
                              void* d_out, int out_size, void* d_ws, size_t ws_size,
                              hipStream_t stream) {
  const float* x    = (const float*)d_in[0];
  const int*   ei   = (const int*)d_in[1];
  const float* W1   = (const float*)d_in[2];
  const float* aS1  = (const float*)d_in[3];
  const float* aD1  = (const float*)d_in[4];
  const float* b1   = (const float*)d_in[5];
  const float* W2   = (const float*)d_in[6];
  const float* aS2  = (const float*)d_in[7];
  const float* aD2  = (const float*)d_in[8];
  const float* b2   = (const float*)d_in[9];
  float* outp = (float*)d_out;

  // ---- workspace layout ----
  char* p = (char*)d_ws;
  float* h1   = (float*)p; p += (size_t)NN * D1 * 4;     // 25.6 MB
  float* z    = (float*)p; p += (size_t)NN * D1 * 4;     // 25.6 MB
  float* as1  = (float*)p; p += (size_t)NN * H1 * 4;
  float* ad1  = (float*)p; p += (size_t)NN * H1 * 4;
  int*   hist   = (int*)p; p += (size_t)NN * 4;
  int*   incl   = (int*)p; p += (size_t)NN * 4;
  int*   rowptr = (int*)p; p += (size_t)(NN + 1) * 4;
  int*   cursor = (int*)p; p += (size_t)NN * 4;
  int*   bsum   = (int*)p; p += 256 * 4;
  int*   boff   = (int*)p; p += 256 * 4;
  unsigned short* srcs = (unsigned short*)p; p += (size_t)ET * 2;
  // layer-2 tensors alias h1 (dead after agg1)
  float* h2  = h1;                       // NN*C2
  float* as2 = h1 + (size_t)NN * C2;     // NN
  float* ad2 = as2 + NN;                 // NN

  hipMemsetAsync(hist, 0, (size_t)NN * 4, stream);

  // CSR build
  hist_k   <<<cdiv_ll(ET, 256), 256, 0, stream>>>(ei, hist);
  scan1_k  <<<NB1, 256, 0, stream>>>(hist, incl, bsum);
  scan2_k  <<<1, 256, 0, stream>>>(bsum, boff);
  scan3_k  <<<NB1, 256, 0, stream>>>(hist, incl, boff, rowptr, cursor);
  scatter_k<<<cdiv_ll(ET, 256), 256, 0, stream>>>(ei, cursor, srcs);

  // layer 1
  gemm1_k<<<cdiv_ll(NN, 64), 256, 0, stream>>>(x, W1, aS1, aD1, h1, as1, ad1);
  agg1_k <<<NN, 128, 0, stream>>>(rowptr, srcs, h1, as1, ad1, b1, z);

  // layer 2
  gemm2_k<<<NN / 16, 256, 0, stream>>>(z, W2, aS2, aD2, h2, as2, ad2);
  agg2_k <<<NN / 16, 256, 0, stream>>>(rowptr, srcs, h2, as2, ad2, b2, outp);
}

// Round 4
// 390.430 us; speedup vs baseline: 4.9486x; 1.1693x over previous
//
#include <hip/hip_runtime.h>
#include <hip/hip_bf16.h>

#define NN 50000
#define NE 1600000
#define ET (NE + NN)   // 1,650,000 incl. self loops
#define H1 8
#define C1 16
#define D1 128
#define C2 16
#define NB1 196        // ceil(NN/256)
#define OCTW 6250      // NN/8 dsts per octant

static inline int cdiv_ll(long long a, int b) { return (int)((a + b - 1) / b); }

// ============ CSR build (XCD-octant-localized) ============
// blocks with blockIdx%8==oct sweep the full dst list; only edges whose dst is
// in [oct*OCTW,(oct+1)*OCTW) are counted -> hist/cursor/srcs regions stay in
// one XCD's L2 (default dispatch round-robins blockIdx across the 8 XCDs).
__global__ __launch_bounds__(256) void hist_oct_k(const int* __restrict__ ei,
                                                  int* __restrict__ hist) {
  const int oct = blockIdx.x & 7;
  const int vb  = blockIdx.x >> 3;
  const int nvb = gridDim.x >> 3;
  const int lo = oct * OCTW, hi = lo + OCTW;
  const int4* d4 = (const int4*)(ei + NE);
  for (int g = vb * 256 + threadIdx.x; g < NE / 4; g += nvb * 256) {
    int4 dd = d4[g];
    if (dd.x >= lo && dd.x < hi) atomicAdd(&hist[dd.x], 1);
    if (dd.y >= lo && dd.y < hi) atomicAdd(&hist[dd.y], 1);
    if (dd.z >= lo && dd.z < hi) atomicAdd(&hist[dd.z], 1);
    if (dd.w >= lo && dd.w < hi) atomicAdd(&hist[dd.w], 1);
  }
}

// inclusive scan of (hist[i]+1): +1 reserves the self-loop slot per node
__global__ __launch_bounds__(256) void scan1_k(const int* __restrict__ hist, int* __restrict__ incl,
                                               int* __restrict__ bsum) {
  __shared__ int sm[256];
  int t = threadIdx.x, i = blockIdx.x * 256 + t;
  int v = (i < NN) ? hist[i] + 1 : 0;
  sm[t] = v; __syncthreads();
  for (int off = 1; off < 256; off <<= 1) {
    int u = (t >= off) ? sm[t - off] : 0;
    __syncthreads();
    sm[t] += u;
    __syncthreads();
  }
  if (i < NN) incl[i] = sm[t];
  if (t == 255) bsum[blockIdx.x] = sm[255];
}

__global__ __launch_bounds__(256) void scan2_k(const int* __restrict__ bsum, int* __restrict__ boff) {
  __shared__ int sm[256];
  int t = threadIdx.x;
  int v = (t < NB1) ? bsum[t] : 0;
  sm[t] = v; __syncthreads();
  for (int off = 1; off < 256; off <<= 1) {
    int u = (t >= off) ? sm[t - off] : 0;
    __syncthreads();
    sm[t] += u;
    __syncthreads();
  }
  if (t < NB1) boff[t] = sm[t] - v;   // exclusive
}

__global__ __launch_bounds__(256) void scan3_k(const int* __restrict__ hist, const int* __restrict__ incl,
                                               const int* __restrict__ boff, int* __restrict__ rowptr,
                                               int* __restrict__ cursor) {
  int i = blockIdx.x * 256 + threadIdx.x;
  if (i >= NN) return;
  int r = incl[i] - (hist[i] + 1) + boff[i >> 8];   // exclusive scan
  rowptr[i] = r;
  cursor[i] = r;
  if (i == 0) rowptr[NN] = ET;
}

// self-loop goes in the last slot of each segment (order within segment is free)
__global__ __launch_bounds__(256) void selfloop_k(const int* __restrict__ rowptr,
                                                  unsigned short* __restrict__ srcs) {
  int i = blockIdx.x * 256 + threadIdx.x;
  if (i < NN) srcs[rowptr[i + 1] - 1] = (unsigned short)i;
}

__global__ __launch_bounds__(256) void scatter_oct_k(const int* __restrict__ ei,
                                                     int* __restrict__ cursor,
                                                     unsigned short* __restrict__ srcs) {
  const int oct = blockIdx.x & 7;
  const int vb  = blockIdx.x >> 3;
  const int nvb = gridDim.x >> 3;
  const int lo = oct * OCTW, hi = lo + OCTW;
  const int4* s4 = (const int4*)ei;
  const int4* d4 = (const int4*)(ei + NE);
  for (int g = vb * 256 + threadIdx.x; g < NE / 4; g += nvb * 256) {
    int4 dd = d4[g];
    int4 ss = s4[g];
    if (dd.x >= lo && dd.x < hi) srcs[atomicAdd(&cursor[dd.x], 1)] = (unsigned short)ss.x;
    if (dd.y >= lo && dd.y < hi) srcs[atomicAdd(&cursor[dd.y], 1)] = (unsigned short)ss.y;
    if (dd.z >= lo && dd.z < hi) srcs[atomicAdd(&cursor[dd.z], 1)] = (unsigned short)ss.z;
    if (dd.w >= lo && dd.w < hi) srcs[atomicAdd(&cursor[dd.w], 1)] = (unsigned short)ss.w;
  }
}

// ============ layer 1 GEMM + fused alpha1, bf16 h1 output ============
__global__ __launch_bounds__(256) void gemm1_k(const float* __restrict__ X,
    const float* __restrict__ W, const float* __restrict__ aS,
    const float* __restrict__ aD, __hip_bfloat16* __restrict__ Yb,
    float* __restrict__ as1, float* __restrict__ ad1) {
  __shared__ float Xs[32][68];
  __shared__ float Wt[32][128];
  const int tid = threadIdx.x;
  const int tx = tid & 31;
  const int ty = tid >> 5;
  const int row0 = blockIdx.x * 64;
  float acc[8][4] = {};

  for (int kt = 0; kt < D1; kt += 32) {
    {
      int r = tid >> 3, c4 = tid & 7;
#pragma unroll
      for (int it = 0; it < 2; ++it) {
        int row = r + it * 32;
        int grow = row0 + row; if (grow > NN - 1) grow = NN - 1;
        float4 v = *(const float4*)(X + (size_t)grow * D1 + kt + c4 * 4);
        Xs[c4 * 4 + 0][row] = v.x; Xs[c4 * 4 + 1][row] = v.y;
        Xs[c4 * 4 + 2][row] = v.z; Xs[c4 * 4 + 3][row] = v.w;
      }
    }
#pragma unroll
    for (int it = 0; it < 4; ++it) {
      int idx = it * 256 + tid;
      int kk = idx >> 5, cc = (idx & 31) * 4;
      *(float4*)&Wt[kk][cc] = *(const float4*)(W + (size_t)(kt + kk) * D1 + cc);
    }
    __syncthreads();
#pragma unroll
    for (int k = 0; k < 32; ++k) {
      float4 w4 = *(const float4*)&Wt[k][tx * 4];
      float4 xa = *(const float4*)&Xs[k][ty * 8];
      float4 xb = *(const float4*)&Xs[k][ty * 8 + 4];
      float xv[8] = {xa.x, xa.y, xa.z, xa.w, xb.x, xb.y, xb.z, xb.w};
      float wv[4] = {w4.x, w4.y, w4.z, w4.w};
#pragma unroll
      for (int rr = 0; rr < 8; ++rr)
#pragma unroll
        for (int cc = 0; cc < 4; ++cc)
          acc[rr][cc] = fmaf(xv[rr], wv[cc], acc[rr][cc]);
    }
    __syncthreads();
  }

  const int h = tx >> 2;
  const int cin = (tx * 4) & 15;
  float a_sv[4], a_dv[4];
#pragma unroll
  for (int j = 0; j < 4; ++j) { a_sv[j] = aS[h * 16 + cin + j]; a_dv[j] = aD[h * 16 + cin + j]; }
#pragma unroll
  for (int rr = 0; rr < 8; ++rr) {
    int grow = row0 + ty * 8 + rr;
    if (grow < NN) {
      union { ushort4 u; __hip_bfloat16 hh[4]; } pk;
      pk.hh[0] = __float2bfloat16(acc[rr][0]);
      pk.hh[1] = __float2bfloat16(acc[rr][1]);
      pk.hh[2] = __float2bfloat16(acc[rr][2]);
      pk.hh[3] = __float2bfloat16(acc[rr][3]);
      *(ushort4*)(Yb + (size_t)grow * D1 + tx * 4) = pk.u;
      float ps = acc[rr][0] * a_sv[0] + acc[rr][1] * a_sv[1] + acc[rr][2] * a_sv[2] + acc[rr][3] * a_sv[3];
      float pd = acc[rr][0] * a_dv[0] + acc[rr][1] * a_dv[1] + acc[rr][2] * a_dv[2] + acc[rr][3] * a_dv[3];
      ps += __shfl_xor(ps, 1); pd += __shfl_xor(pd, 1);
      ps += __shfl_xor(ps, 2); pd += __shfl_xor(pd, 2);
      if ((tx & 3) == 0) { as1[grow * H1 + h] = ps; ad1[grow * H1 + h] = pd; }
    }
  }
}

// ============ fused layer-1 aggregation ============
// Per 128-edge batch: thread t computes the 8 head-weights of edge t (kills the
// 16x redundant expf), j-loop reads them via LDS broadcast; h1 payload is bf16.
__global__ __launch_bounds__(128) void agg1_k(const int* __restrict__ rowptr,
    const unsigned short* __restrict__ srcs, const __hip_bfloat16* __restrict__ h1b,
    const float* __restrict__ as, const float* __restrict__ ad,
    const float* __restrict__ b, float* __restrict__ z) {
  __shared__ int ssrc[128];
  __shared__ float wl[128 * 9];   // stride 9 -> conflict-free scalar writes
  const int d = blockIdx.x;
  const int ch = threadIdx.x;
  const int h = ch >> 4;
  const int beg = rowptr[d], end = rowptr[d + 1];
  const float4 adv0 = *(const float4*)(ad + (size_t)d * H1);
  const float4 adv1 = *(const float4*)(ad + (size_t)d * H1 + 4);
  float acc0 = 0, acc1 = 0, acc2 = 0, acc3 = 0;
  float den0 = 0, den1 = 0, den2 = 0, den3 = 0;
  for (int base = beg; base < end; base += 128) {
    int m = min(128, end - base);
    if (ch < m) ssrc[ch] = (int)srcs[base + ch];
    __syncthreads();
    if (ch < m) {
      int s = ssrc[ch];
      const float4 a0 = *(const float4*)(as + (size_t)s * H1);
      const float4 a1 = *(const float4*)(as + (size_t)s * H1 + 4);
      float* wp = &wl[ch * 9];
      float e;
      e = a0.x + adv0.x; e = e > 0.f ? e : 0.2f * e; wp[0] = __expf(e);
      e = a0.y + adv0.y; e = e > 0.f ? e : 0.2f * e; wp[1] = __expf(e);
      e = a0.z + adv0.z; e = e > 0.f ? e : 0.2f * e; wp[2] = __expf(e);
      e = a0.w + adv0.w; e = e > 0.f ? e : 0.2f * e; wp[3] = __expf(e);
      e = a1.x + adv1.x; e = e > 0.f ? e : 0.2f * e; wp[4] = __expf(e);
      e = a1.y + adv1.y; e = e > 0.f ? e : 0.2f * e; wp[5] = __expf(e);
      e = a1.z + adv1.z; e = e > 0.f ? e : 0.2f * e; wp[6] = __expf(e);
      e = a1.w + adv1.w; e = e > 0.f ? e : 0.2f * e; wp[7] = __expf(e);
    }
    __syncthreads();
    int j = 0;
    for (; j + 4 <= m; j += 4) {
      int s0 = ssrc[j], s1 = ssrc[j + 1], s2 = ssrc[j + 2], s3 = ssrc[j + 3];
      float w0 = wl[(j + 0) * 9 + h], w1 = wl[(j + 1) * 9 + h];
      float w2 = wl[(j + 2) * 9 + h], w3 = wl[(j + 3) * 9 + h];
      den0 += w0; den1 += w1; den2 += w2; den3 += w3;
      acc0 = fmaf(w0, __bfloat162float(h1b[(size_t)s0 * D1 + ch]), acc0);
      acc1 = fmaf(w1, __bfloat162float(h1b[(size_t)s1 * D1 + ch]), acc1);
      acc2 = fmaf(w2, __bfloat162float(h1b[(size_t)s2 * D1 + ch]), acc2);
      acc3 = fmaf(w3, __bfloat162float(h1b[(size_t)s3 * D1 + ch]), acc3);
    }
    for (; j < m; ++j) {
      int s0 = ssrc[j];
      float w0 = wl[j * 9 + h];
      den0 += w0;
      acc0 = fmaf(w0, __bfloat162float(h1b[(size_t)s0 * D1 + ch]), acc0);
    }
    __syncthreads();
  }
  float den = (den0 + den1) + (den2 + den3);
  float acc = (acc0 + acc1) + (acc2 + acc3);
  float v = acc / den + b[ch];
  z[(size_t)d * D1 + ch] = v > 0.f ? v : __expf(v) - 1.f;
}

// ============ layer 2 GEMM + fused alpha2 ============
__global__ __launch_bounds__(256) void gemm2_k(const float* __restrict__ Z,
    const float* __restrict__ W, const float* __restrict__ aS,
    const float* __restrict__ aD, float* __restrict__ Y,
    float* __restrict__ as2, float* __restrict__ ad2) {
  __shared__ float Ws[D1][C2];
  __shared__ float Zs[16][D1 + 4];
  const int tid = threadIdx.x;
  for (int i = tid; i < D1 * C2; i += 256) Ws[i >> 4][i & 15] = W[i];
  const int rb = blockIdx.x * 16;
  {
    int r = tid >> 5, c4 = (tid & 31) * 4;
#pragma unroll
    for (int it = 0; it < 2; ++it) {
      int rr = r + it * 8;
      float4 v = *(const float4*)(Z + (size_t)(rb + rr) * D1 + c4);
      *(float4*)&Zs[rr][c4] = v;
    }
  }
  __syncthreads();
  const int r = tid >> 4, c = tid & 15;
  float a0 = 0, a1 = 0, a2 = 0, a3 = 0;
#pragma unroll
  for (int k = 0; k < D1; k += 4) {
    float4 z4 = *(const float4*)&Zs[r][k];
    a0 = fmaf(z4.x, Ws[k][c], a0);
    a1 = fmaf(z4.y, Ws[k + 1][c], a1);
    a2 = fmaf(z4.z, Ws[k + 2][c], a2);
    a3 = fmaf(z4.w, Ws[k + 3][c], a3);
  }
  float acc = (a0 + a1) + (a2 + a3);
  Y[(size_t)(rb + r) * C2 + c] = acc;
  float ps = acc * aS[c], pd = acc * aD[c];
  ps += __shfl_xor(ps, 1); pd += __shfl_xor(pd, 1);
  ps += __shfl_xor(ps, 2); pd += __shfl_xor(pd, 2);
  ps += __shfl_xor(ps, 4); pd += __shfl_xor(pd, 4);
  ps += __shfl_xor(ps, 8); pd += __shfl_xor(pd, 8);
  if (c == 0) { as2[rb + r] = ps; ad2[rb + r] = pd; }
}

// ============ fused layer-2 aggregation ============
__global__ __launch_bounds__(256) void agg2_k(const int* __restrict__ rowptr,
    const unsigned short* __restrict__ srcs, const float* __restrict__ h2,
    const float* __restrict__ as, const float* __restrict__ ad,
    const float* __restrict__ b, float* __restrict__ outp) {
  const int d = blockIdx.x * 16 + (threadIdx.x >> 4);
  const int ch = threadIdx.x & 15;
  const int beg = rowptr[d], end = rowptr[d + 1];
  const float add = ad[d];
  float acc0 = 0, acc1 = 0, acc2 = 0, acc3 = 0;
  float den0 = 0, den1 = 0, den2 = 0, den3 = 0;
  int j = beg;
  for (; j + 4 <= end; j += 4) {
    int s0 = srcs[j], s1 = srcs[j + 1], s2 = srcs[j + 2], s3 = srcs[j + 3];
    float e0 = as[s0] + add, e1 = as[s1] + add, e2 = as[s2] + add, e3 = as[s3] + add;
    e0 = e0 > 0.f ? e0 : 0.2f * e0; e1 = e1 > 0.f ? e1 : 0.2f * e1;
    e2 = e2 > 0.f ? e2 : 0.2f * e2; e3 = e3 > 0.f ? e3 : 0.2f * e3;
    float w0 = __expf(e0), w1 = __expf(e1), w2 = __expf(e2), w3 = __expf(e3);
    den0 += w0; den1 += w1; den2 += w2; den3 += w3;
    acc0 = fmaf(w0, h2[(size_t)s0 * C2 + ch], acc0);
    acc1 = fmaf(w1, h2[(size_t)s1 * C2 + ch], acc1);
    acc2 = fmaf(w2, h2[(size_t)s2 * C2 + ch], acc2);
    acc3 = fmaf(w3, h2[(size_t)s3 * C2 + ch], acc3);
  }
  for (; j < end; ++j) {
    int s0 = srcs[j];
    float e0 = as[s0] + add;
    e0 = e0 > 0.f ? e0 : 0.2f * e0;
    float w0 = __expf(e0);
    den0 += w0;
    acc0 = fmaf(w0, h2[(size_t)s0 * C2 + ch], acc0);
  }
  outp[(size_t)d * C2 + ch] = ((acc0 + acc1) + (acc2 + acc3)) / ((den0 + den1) + (den2 + den3)) + b[ch];
}

extern "C" void kernel_launch(void* const* d_in, const int* in_sizes, int n_in,
                              void* d_out, int out_size, void* d_ws, size_t ws_size,
                              hipStream_t stream) {
  const float* x    = (const float*)d_in[0];
  const int*   ei   = (const int*)d_in[1];
  const float* W1   = (const float*)d_in[2];
  const float* aS1  = (const float*)d_in[3];
  const float* aD1  = (const float*)d_in[4];
  const float* b1   = (const float*)d_in[5];
  const float* W2   = (const float*)d_in[6];
  const float* aS2  = (const float*)d_in[7];
  const float* aD2  = (const float*)d_in[8];
  const float* b2   = (const float*)d_in[9];
  float* outp = (float*)d_out;

  // ---- workspace layout ----
  char* p = (char*)d_ws;
  __hip_bfloat16* h1b = (__hip_bfloat16*)p; p += (size_t)NN * D1 * 2;  // 12.8 MB
  float* z    = (float*)p; p += (size_t)NN * D1 * 4;                    // 25.6 MB
  float* as1  = (float*)p; p += (size_t)NN * H1 * 4;
  float* ad1  = (float*)p; p += (size_t)NN * H1 * 4;
  int*   hist   = (int*)p; p += (size_t)NN * 4;
  int*   incl   = (int*)p; p += (size_t)NN * 4;
  int*   rowptr = (int*)p; p += (size_t)(NN + 1) * 4;
  int*   cursor = (int*)p; p += (size_t)NN * 4;
  int*   bsum   = (int*)p; p += 256 * 4;
  int*   boff   = (int*)p; p += 256 * 4;
  unsigned short* srcs = (unsigned short*)p; p += (size_t)ET * 2;
  // layer-2 tensors alias h1b region (dead after agg1): need 3.6 MB < 12.8 MB
  float* h2  = (float*)h1b;                   // NN*C2 fp32
  float* as2 = h2 + (size_t)NN * C2;
  float* ad2 = as2 + NN;

  hipMemsetAsync(hist, 0, (size_t)NN * 4, stream);

  // CSR build (octant-localized)
  hist_oct_k   <<<2048, 256, 0, stream>>>(ei, hist);
  scan1_k      <<<NB1, 256, 0, stream>>>(hist, incl, bsum);
  scan2_k      <<<1, 256, 0, stream>>>(bsum, boff);
  scan3_k      <<<NB1, 256, 0, stream>>>(hist, incl, boff, rowptr, cursor);
  selfloop_k   <<<NB1, 256, 0, stream>>>(rowptr, srcs);
  scatter_oct_k<<<2048, 256, 0, stream>>>(ei, cursor, srcs);

  // layer 1
  gemm1_k<<<cdiv_ll(NN, 64), 256, 0, stream>>>(x, W1, aS1, aD1, h1b, as1, ad1);
  agg1_k <<<NN, 128, 0, stream>>>(rowptr, srcs, h1b, as1, ad1, b1, z);

  // layer 2
  gemm2_k<<<NN / 16, 256, 0, stream>>>(z, W2, aS2, aD2, h2, as2, ad2);
  agg2_k <<<NN / 16, 256, 0, stream>>>(rowptr, srcs, h2, as2, ad2, b2, outp);
}

// Round 5
// 380.145 us; speedup vs baseline: 5.0825x; 1.0271x over previous
//
#include <hip/hip_runtime.h>
#include <hip/hip_bf16.h>

#define NN 50000
#define NE 1600000
#define ET (NE + NN)   // 1,650,000 incl. self loops
#define H1 8
#define C1 16
#define D1 128
#define C2 16
#define NB1 196        // ceil(NN/256)
#define OCTW 6250      // NN/8 dsts per octant

typedef unsigned short u16;
typedef unsigned int u32;

static inline int cdiv_ll(long long a, int b) { return (int)((a + b - 1) / b); }

// ============ pack src/dst to u16 (one coalesced pass; halves octant sweeps) ============
__global__ __launch_bounds__(256) void pack_k(const int* __restrict__ ei,
                                              u16* __restrict__ src16, u16* __restrict__ dst16) {
  int i = blockIdx.x * 256 + threadIdx.x;
  if (i >= NE / 4) return;
  int4 s = ((const int4*)ei)[i];
  int4 d = ((const int4*)(ei + NE))[i];
  ushort4 sp; sp.x = (u16)s.x; sp.y = (u16)s.y; sp.z = (u16)s.z; sp.w = (u16)s.w;
  ushort4 dp; dp.x = (u16)d.x; dp.y = (u16)d.y; dp.z = (u16)d.z; dp.w = (u16)d.w;
  ((ushort4*)src16)[i] = sp;
  ((ushort4*)dst16)[i] = dp;
}

// ============ CSR build (XCD-octant-localized) ============
__global__ __launch_bounds__(256) void hist_oct_k(const u16* __restrict__ dst16,
                                                  int* __restrict__ hist) {
  const int oct = blockIdx.x & 7;
  const int vb  = blockIdx.x >> 3;
  const int nvb = gridDim.x >> 3;
  const int lo = oct * OCTW, hi = lo + OCTW;
  const uint4* d8 = (const uint4*)dst16;   // 8 edges per load
  for (int g = vb * 256 + threadIdx.x; g < NE / 8; g += nvb * 256) {
    uint4 v = d8[g];
    int d0 = v.x & 0xffff, d1 = v.x >> 16, d2 = v.y & 0xffff, d3 = v.y >> 16;
    int d4 = v.z & 0xffff, d5 = v.z >> 16, d6 = v.w & 0xffff, d7 = v.w >> 16;
    if (d0 >= lo && d0 < hi) atomicAdd(&hist[d0], 1);
    if (d1 >= lo && d1 < hi) atomicAdd(&hist[d1], 1);
    if (d2 >= lo && d2 < hi) atomicAdd(&hist[d2], 1);
    if (d3 >= lo && d3 < hi) atomicAdd(&hist[d3], 1);
    if (d4 >= lo && d4 < hi) atomicAdd(&hist[d4], 1);
    if (d5 >= lo && d5 < hi) atomicAdd(&hist[d5], 1);
    if (d6 >= lo && d6 < hi) atomicAdd(&hist[d6], 1);
    if (d7 >= lo && d7 < hi) atomicAdd(&hist[d7], 1);
  }
}

// inclusive scan of (hist[i]+1): +1 reserves the self-loop slot per node
__global__ __launch_bounds__(256) void scan1_k(const int* __restrict__ hist, int* __restrict__ incl,
                                               int* __restrict__ bsum) {
  __shared__ int sm[256];
  int t = threadIdx.x, i = blockIdx.x * 256 + t;
  int v = (i < NN) ? hist[i] + 1 : 0;
  sm[t] = v; __syncthreads();
  for (int off = 1; off < 256; off <<= 1) {
    int u = (t >= off) ? sm[t - off] : 0;
    __syncthreads();
    sm[t] += u;
    __syncthreads();
  }
  if (i < NN) incl[i] = sm[t];
  if (t == 255) bsum[blockIdx.x] = sm[255];
}

__global__ __launch_bounds__(256) void scan2_k(const int* __restrict__ bsum, int* __restrict__ boff) {
  __shared__ int sm[256];
  int t = threadIdx.x;
  int v = (t < NB1) ? bsum[t] : 0;
  sm[t] = v; __syncthreads();
  for (int off = 1; off < 256; off <<= 1) {
    int u = (t >= off) ? sm[t - off] : 0;
    __syncthreads();
    sm[t] += u;
    __syncthreads();
  }
  if (t < NB1) boff[t] = sm[t] - v;   // exclusive
}

__global__ __launch_bounds__(256) void scan3_k(const int* __restrict__ hist, const int* __restrict__ incl,
                                               const int* __restrict__ boff, int* __restrict__ rowptr,
                                               int* __restrict__ cursor) {
  int i = blockIdx.x * 256 + threadIdx.x;
  if (i >= NN) return;
  int r = incl[i] - (hist[i] + 1) + boff[i >> 8];   // exclusive scan
  rowptr[i] = r;
  cursor[i] = r;
  if (i == 0) rowptr[NN] = ET;
}

__global__ __launch_bounds__(256) void selfloop_k(const int* __restrict__ rowptr,
                                                  u16* __restrict__ srcs) {
  int i = blockIdx.x * 256 + threadIdx.x;
  if (i < NN) srcs[rowptr[i + 1] - 1] = (u16)i;
}

__global__ __launch_bounds__(256) void scatter_oct_k(const u16* __restrict__ src16,
                                                     const u16* __restrict__ dst16,
                                                     int* __restrict__ cursor,
                                                     u16* __restrict__ srcs) {
  const int oct = blockIdx.x & 7;
  const int vb  = blockIdx.x >> 3;
  const int nvb = gridDim.x >> 3;
  const int lo = oct * OCTW, hi = lo + OCTW;
  const uint4* d8 = (const uint4*)dst16;
  const uint4* s8 = (const uint4*)src16;
  for (int g = vb * 256 + threadIdx.x; g < NE / 8; g += nvb * 256) {
    uint4 dv = d8[g];
    uint4 sv = s8[g];
    int dd[8] = {(int)(dv.x & 0xffff), (int)(dv.x >> 16), (int)(dv.y & 0xffff), (int)(dv.y >> 16),
                 (int)(dv.z & 0xffff), (int)(dv.z >> 16), (int)(dv.w & 0xffff), (int)(dv.w >> 16)};
    u16 ss[8] = {(u16)(sv.x & 0xffff), (u16)(sv.x >> 16), (u16)(sv.y & 0xffff), (u16)(sv.y >> 16),
                 (u16)(sv.z & 0xffff), (u16)(sv.z >> 16), (u16)(sv.w & 0xffff), (u16)(sv.w >> 16)};
#pragma unroll
    for (int q = 0; q < 8; ++q)
      if (dd[q] >= lo && dd[q] < hi) srcs[atomicAdd(&cursor[dd[q]], 1)] = ss[q];
  }
}

// ============ layer 1 GEMM + fused alpha1, bf16 h1 output ============
__global__ __launch_bounds__(256) void gemm1_k(const float* __restrict__ X,
    const float* __restrict__ W, const float* __restrict__ aS,
    const float* __restrict__ aD, __hip_bfloat16* __restrict__ Yb,
    float* __restrict__ as1, float* __restrict__ ad1) {
  __shared__ float Xs[32][68];
  __shared__ float Wt[32][128];
  const int tid = threadIdx.x;
  const int tx = tid & 31;
  const int ty = tid >> 5;
  const int row0 = blockIdx.x * 64;
  float acc[8][4] = {};

  for (int kt = 0; kt < D1; kt += 32) {
    {
      int r = tid >> 3, c4 = tid & 7;
#pragma unroll
      for (int it = 0; it < 2; ++it) {
        int row = r + it * 32;
        int grow = row0 + row; if (grow > NN - 1) grow = NN - 1;
        float4 v = *(const float4*)(X + (size_t)grow * D1 + kt + c4 * 4);
        Xs[c4 * 4 + 0][row] = v.x; Xs[c4 * 4 + 1][row] = v.y;
        Xs[c4 * 4 + 2][row] = v.z; Xs[c4 * 4 + 3][row] = v.w;
      }
    }
#pragma unroll
    for (int it = 0; it < 4; ++it) {
      int idx = it * 256 + tid;
      int kk = idx >> 5, cc = (idx & 31) * 4;
      *(float4*)&Wt[kk][cc] = *(const float4*)(W + (size_t)(kt + kk) * D1 + cc);
    }
    __syncthreads();
#pragma unroll
    for (int k = 0; k < 32; ++k) {
      float4 w4 = *(const float4*)&Wt[k][tx * 4];
      float4 xa = *(const float4*)&Xs[k][ty * 8];
      float4 xb = *(const float4*)&Xs[k][ty * 8 + 4];
      float xv[8] = {xa.x, xa.y, xa.z, xa.w, xb.x, xb.y, xb.z, xb.w};
      float wv[4] = {w4.x, w4.y, w4.z, w4.w};
#pragma unroll
      for (int rr = 0; rr < 8; ++rr)
#pragma unroll
        for (int cc = 0; cc < 4; ++cc)
          acc[rr][cc] = fmaf(xv[rr], wv[cc], acc[rr][cc]);
    }
    __syncthreads();
  }

  const int h = tx >> 2;
  const int cin = (tx * 4) & 15;
  float a_sv[4], a_dv[4];
#pragma unroll
  for (int j = 0; j < 4; ++j) { a_sv[j] = aS[h * 16 + cin + j]; a_dv[j] = aD[h * 16 + cin + j]; }
#pragma unroll
  for (int rr = 0; rr < 8; ++rr) {
    int grow = row0 + ty * 8 + rr;
    if (grow < NN) {
      union { ushort4 u; __hip_bfloat16 hh[4]; } pk;
      pk.hh[0] = __float2bfloat16(acc[rr][0]);
      pk.hh[1] = __float2bfloat16(acc[rr][1]);
      pk.hh[2] = __float2bfloat16(acc[rr][2]);
      pk.hh[3] = __float2bfloat16(acc[rr][3]);
      *(ushort4*)(Yb + (size_t)grow * D1 + tx * 4) = pk.u;
      float ps = acc[rr][0] * a_sv[0] + acc[rr][1] * a_sv[1] + acc[rr][2] * a_sv[2] + acc[rr][3] * a_sv[3];
      float pd = acc[rr][0] * a_dv[0] + acc[rr][1] * a_dv[1] + acc[rr][2] * a_dv[2] + acc[rr][3] * a_dv[3];
      ps += __shfl_xor(ps, 1); pd += __shfl_xor(pd, 1);
      ps += __shfl_xor(ps, 2); pd += __shfl_xor(pd, 2);
      if ((tx & 3) == 0) { as1[grow * H1 + h] = ps; ad1[grow * H1 + h] = pd; }
    }
  }
}

// ============ fused layer-1 aggregation: 1 wave per dst, 2 ch per lane ============
// lane loads uint (2 bf16), decodes with 2 shifts; lane t computes edge t's 8
// head-weights from its own register (no extra barrier); 2 dsts per 128-thr block.
__global__ __launch_bounds__(128) void agg1_k(const int* __restrict__ rowptr,
    const u16* __restrict__ srcs, const u32* __restrict__ h1u,
    const float* __restrict__ as, const float* __restrict__ ad,
    const float* __restrict__ b, float* __restrict__ z) {
  __shared__ int ssrc[2][64];
  __shared__ float wl[2][64 * 9];
  __shared__ int lens[2];
  const int w = threadIdx.x >> 6;
  const int lane = threadIdx.x & 63;
  const int d = blockIdx.x * 2 + w;
  const int h = lane >> 3;                 // head of channels {2*lane, 2*lane+1}
  const int beg = rowptr[d], end = rowptr[d + 1];
  if (lane == 0) lens[w] = end - beg;
  __syncthreads();
  const int nb = (max(lens[0], lens[1]) + 63) >> 6;
  const float4 adv0 = *(const float4*)(ad + (size_t)d * H1);
  const float4 adv1 = *(const float4*)(ad + (size_t)d * H1 + 4);
  float aL0 = 0, aL1 = 0, aL2 = 0, aL3 = 0;
  float aH0 = 0, aH1 = 0, aH2 = 0, aH3 = 0;
  float dn0 = 0, dn1 = 0, dn2 = 0, dn3 = 0;
  for (int it = 0; it < nb; ++it) {
    const int base = beg + (it << 6);
    int m = end - base; m = m < 0 ? 0 : (m > 64 ? 64 : m);
    if (lane < m) {
      int s = (int)srcs[base + lane];
      ssrc[w][lane] = s;
      const float4 a0 = *(const float4*)(as + (size_t)s * H1);
      const float4 a1 = *(const float4*)(as + (size_t)s * H1 + 4);
      float* wp = &wl[w][lane * 9];
      float e;
      e = a0.x + adv0.x; e = e > 0.f ? e : 0.2f * e; wp[0] = __expf(e);
      e = a0.y + adv0.y; e = e > 0.f ? e : 0.2f * e; wp[1] = __expf(e);
      e = a0.z + adv0.z; e = e > 0.f ? e : 0.2f * e; wp[2] = __expf(e);
      e = a0.w + adv0.w; e = e > 0.f ? e : 0.2f * e; wp[3] = __expf(e);
      e = a1.x + adv1.x; e = e > 0.f ? e : 0.2f * e; wp[4] = __expf(e);
      e = a1.y + adv1.y; e = e > 0.f ? e : 0.2f * e; wp[5] = __expf(e);
      e = a1.z + adv1.z; e = e > 0.f ? e : 0.2f * e; wp[6] = __expf(e);
      e = a1.w + adv1.w; e = e > 0.f ? e : 0.2f * e; wp[7] = __expf(e);
    }
    __syncthreads();
    int j = 0;
    for (; j + 4 <= m; j += 4) {
      int s0 = ssrc[w][j], s1 = ssrc[w][j + 1], s2 = ssrc[w][j + 2], s3 = ssrc[w][j + 3];
      float w0 = wl[w][(j + 0) * 9 + h], w1 = wl[w][(j + 1) * 9 + h];
      float w2 = wl[w][(j + 2) * 9 + h], w3 = wl[w][(j + 3) * 9 + h];
      u32 v0 = h1u[(size_t)s0 * 64 + lane];
      u32 v1 = h1u[(size_t)s1 * 64 + lane];
      u32 v2 = h1u[(size_t)s2 * 64 + lane];
      u32 v3 = h1u[(size_t)s3 * 64 + lane];
      dn0 += w0; dn1 += w1; dn2 += w2; dn3 += w3;
      aL0 = fmaf(w0, __uint_as_float(v0 << 16), aL0);
      aH0 = fmaf(w0, __uint_as_float(v0 & 0xffff0000u), aH0);
      aL1 = fmaf(w1, __uint_as_float(v1 << 16), aL1);
      aH1 = fmaf(w1, __uint_as_float(v1 & 0xffff0000u), aH1);
      aL2 = fmaf(w2, __uint_as_float(v2 << 16), aL2);
      aH2 = fmaf(w2, __uint_as_float(v2 & 0xffff0000u), aH2);
      aL3 = fmaf(w3, __uint_as_float(v3 << 16), aL3);
      aH3 = fmaf(w3, __uint_as_float(v3 & 0xffff0000u), aH3);
    }
    for (; j < m; ++j) {
      int s0 = ssrc[w][j];
      float w0 = wl[w][j * 9 + h];
      u32 v0 = h1u[(size_t)s0 * 64 + lane];
      dn0 += w0;
      aL0 = fmaf(w0, __uint_as_float(v0 << 16), aL0);
      aH0 = fmaf(w0, __uint_as_float(v0 & 0xffff0000u), aH0);
    }
    __syncthreads();
  }
  float den = (dn0 + dn1) + (dn2 + dn3);
  float aL = (aL0 + aL1) + (aL2 + aL3);
  float aH = (aH0 + aH1) + (aH2 + aH3);
  float inv = 1.f / den;
  float2 bb = *(const float2*)(b + lane * 2);
  float v0 = aL * inv + bb.x;
  float v1 = aH * inv + bb.y;
  v0 = v0 > 0.f ? v0 : __expf(v0) - 1.f;
  v1 = v1 > 0.f ? v1 : __expf(v1) - 1.f;
  float2 o = {v0, v1};
  *(float2*)(z + (size_t)d * D1 + lane * 2) = o;
}

// ============ layer 2 GEMM + fused alpha2, bf16 h2 output ============
__global__ __launch_bounds__(256) void gemm2_k(const float* __restrict__ Z,
    const float* __restrict__ W, const float* __restrict__ aS,
    const float* __restrict__ aD, __hip_bfloat16* __restrict__ Yb,
    float* __restrict__ as2, float* __restrict__ ad2) {
  __shared__ float Ws[D1][C2];
  __shared__ float Zs[16][D1 + 4];
  const int tid = threadIdx.x;
  for (int i = tid; i < D1 * C2; i += 256) Ws[i >> 4][i & 15] = W[i];
  const int rb = blockIdx.x * 16;
  {
    int r = tid >> 5, c4 = (tid & 31) * 4;
#pragma unroll
    for (int it = 0; it < 2; ++it) {
      int rr = r + it * 8;
      float4 v = *(const float4*)(Z + (size_t)(rb + rr) * D1 + c4);
      *(float4*)&Zs[rr][c4] = v;
    }
  }
  __syncthreads();
  const int r = tid >> 4, c = tid & 15;
  float a0 = 0, a1 = 0, a2 = 0, a3 = 0;
#pragma unroll
  for (int k = 0; k < D1; k += 4) {
    float4 z4 = *(const float4*)&Zs[r][k];
    a0 = fmaf(z4.x, Ws[k][c], a0);
    a1 = fmaf(z4.y, Ws[k + 1][c], a1);
    a2 = fmaf(z4.z, Ws[k + 2][c], a2);
    a3 = fmaf(z4.w, Ws[k + 3][c], a3);
  }
  float acc = (a0 + a1) + (a2 + a3);
  Yb[(size_t)(rb + r) * C2 + c] = __float2bfloat16(acc);
  float ps = acc * aS[c], pd = acc * aD[c];
  ps += __shfl_xor(ps, 1); pd += __shfl_xor(pd, 1);
  ps += __shfl_xor(ps, 2); pd += __shfl_xor(pd, 2);
  ps += __shfl_xor(ps, 4); pd += __shfl_xor(pd, 4);
  ps += __shfl_xor(ps, 8); pd += __shfl_xor(pd, 8);
  if (c == 0) { as2[rb + r] = ps; ad2[rb + r] = pd; }
}

// ============ fused layer-2 aggregation: wave = 8 edges x 8 ch-pairs, no LDS/barriers ============
__global__ __launch_bounds__(256) void agg2_k(const int* __restrict__ rowptr,
    const u16* __restrict__ srcs, const u32* __restrict__ h2u,
    const float* __restrict__ as, const float* __restrict__ ad,
    const float* __restrict__ b, float* __restrict__ outp) {
  const int wv = threadIdx.x >> 6;
  const int lane = threadIdx.x & 63;
  const int d = blockIdx.x * 4 + wv;
  const int j8 = lane >> 3, cp = lane & 7;   // edge slot, channel pair
  const int beg = rowptr[d], end = rowptr[d + 1];
  const float adv = ad[d];
  float a0 = 0, a1 = 0, den = 0;
  for (int j = beg + j8; j < end; j += 8) {
    int s = (int)srcs[j];
    float e = as[s] + adv;
    e = e > 0.f ? e : 0.2f * e;
    float wgt = __expf(e);
    u32 v = h2u[(size_t)s * 8 + cp];
    den += wgt;
    a0 = fmaf(wgt, __uint_as_float(v << 16), a0);
    a1 = fmaf(wgt, __uint_as_float(v & 0xffff0000u), a1);
  }
#pragma unroll
  for (int off = 8; off < 64; off <<= 1) {
    a0 += __shfl_xor(a0, off);
    a1 += __shfl_xor(a1, off);
    den += __shfl_xor(den, off);
  }
  if (j8 == 0) {
    float inv = 1.f / den;
    float2 bb = *(const float2*)(b + cp * 2);
    float2 o = {a0 * inv + bb.x, a1 * inv + bb.y};
    *(float2*)(outp + (size_t)d * C2 + cp * 2) = o;
  }
}

extern "C" void kernel_launch(void* const* d_in, const int* in_sizes, int n_in,
                              void* d_out, int out_size, void* d_ws, size_t ws_size,
                              hipStream_t stream) {
  const float* x    = (const float*)d_in[0];
  const int*   ei   = (const int*)d_in[1];
  const float* W1   = (const float*)d_in[2];
  const float* aS1  = (const float*)d_in[3];
  const float* aD1  = (const float*)d_in[4];
  const float* b1   = (const float*)d_in[5];
  const float* W2   = (const float*)d_in[6];
  const float* aS2  = (const float*)d_in[7];
  const float* aD2  = (const float*)d_in[8];
  const float* b2   = (const float*)d_in[9];
  float* outp = (float*)d_out;

  // ---- workspace layout ----
  char* p = (char*)d_ws;
  __hip_bfloat16* h1b = (__hip_bfloat16*)p; p += (size_t)NN * D1 * 2;  // 12.8 MB
  float* z    = (float*)p; p += (size_t)NN * D1 * 4;                    // 25.6 MB
  float* as1  = (float*)p; p += (size_t)NN * H1 * 4;
  float* ad1  = (float*)p; p += (size_t)NN * H1 * 4;
  int*   hist   = (int*)p; p += (size_t)NN * 4;
  int*   incl   = (int*)p; p += (size_t)NN * 4;
  int*   rowptr = (int*)p; p += (size_t)(NN + 1) * 4;
  int*   cursor = (int*)p; p += (size_t)NN * 4;
  int*   bsum   = (int*)p; p += 256 * 4;
  int*   boff   = (int*)p; p += 256 * 4;
  u16*   srcs   = (u16*)p; p += (size_t)ET * 2;
  u16*   src16  = (u16*)p; p += (size_t)NE * 2;
  u16*   dst16  = (u16*)p; p += (size_t)NE * 2;
  // layer-2 tensors alias h1b region (dead after agg1)
  __hip_bfloat16* h2b = h1b;                          // NN*C2 bf16
  float* as2 = (float*)(h1b + (size_t)NN * C2);
  float* ad2 = as2 + NN;

  hipMemsetAsync(hist, 0, (size_t)NN * 4, stream);

  // CSR build (octant-localized, u16-packed sweeps)
  pack_k       <<<cdiv_ll(NE / 4, 256), 256, 0, stream>>>(ei, src16, dst16);
  hist_oct_k   <<<2048, 256, 0, stream>>>(dst16, hist);
  scan1_k      <<<NB1, 256, 0, stream>>>(hist, incl, bsum);
  scan2_k      <<<1, 256, 0, stream>>>(bsum, boff);
  scan3_k      <<<NB1, 256, 0, stream>>>(hist, incl, boff, rowptr, cursor);
  selfloop_k   <<<NB1, 256, 0, stream>>>(rowptr, srcs);
  scatter_oct_k<<<2048, 256, 0, stream>>>(src16, dst16, cursor, srcs);

  // layer 1
  gemm1_k<<<cdiv_ll(NN, 64), 256, 0, stream>>>(x, W1, aS1, aD1, h1b, as1, ad1);
  agg1_k <<<NN / 2, 128, 0, stream>>>(rowptr, srcs, (const u32*)h1b, as1, ad1, b1, z);

  // layer 2
  gemm2_k<<<NN / 16, 256, 0, stream>>>(z, W2, aS2, aD2, h2b, as2, ad2);
  agg2_k <<<NN / 4, 256, 0, stream>>>(rowptr, srcs, (const u32*)h2b, as2, ad2, b2, outp);
}

// Round 6
// 336.435 us; speedup vs baseline: 5.7428x; 1.1299x over previous
//
#include <hip/hip_runtime.h>
#include <hip/hip_bf16.h>

#define NN 50000
#define NE 1600000
#define ET (NE + NN)   // 1,650,000 incl. self loops
#define H1 8
#define C1 16
#define D1 128
#define C2 16
#define NB1 196        // ceil(NN/256)
#define OCTW 6250      // NN/8 dsts per octant
#define NSL 16         // slices for atomic-free CSR build
#define SLE (NE / NSL) // 100,000 edges per slice

// K1 role partition
#define GEMM_NB 782    // ceil(50000/64)
#define HIST_NB 128    // 8 octants x 16 slices
#define PACK_NB 1563   // ceil(NE/4/256)

typedef unsigned short u16;
typedef unsigned int u32;
typedef u32 u32x4 __attribute__((ext_vector_type(4)));

static inline int cdiv_i(long long a, int b) { return (int)((a + b - 1) / b); }

// ==================================================================
// K1: fused  [gemm1+alpha1 | slice-hist | pack]  (block-range roles)
// ==================================================================
__device__ void gemm1_role(int bid, char* smem, const float* __restrict__ X,
    const float* __restrict__ W, const float* __restrict__ aS,
    const float* __restrict__ aD, __hip_bfloat16* __restrict__ Yb,
    float* __restrict__ as1, float* __restrict__ ad1) {
  float (*Xs)[68]  = (float(*)[68])smem;            // 32x68 floats = 8704 B
  float (*Wt)[128] = (float(*)[128])(smem + 8704);  // 32x128 floats = 16384 B
  const int tid = threadIdx.x;
  const int tx = tid & 31;
  const int ty = tid >> 5;
  const int row0 = bid * 64;
  float acc[8][4] = {};

  for (int kt = 0; kt < D1; kt += 32) {
    {
      int r = tid >> 3, c4 = tid & 7;
#pragma unroll
      for (int it = 0; it < 2; ++it) {
        int row = r + it * 32;
        int grow = row0 + row; if (grow > NN - 1) grow = NN - 1;
        float4 v = *(const float4*)(X + (size_t)grow * D1 + kt + c4 * 4);
        Xs[c4 * 4 + 0][row] = v.x; Xs[c4 * 4 + 1][row] = v.y;
        Xs[c4 * 4 + 2][row] = v.z; Xs[c4 * 4 + 3][row] = v.w;
      }
    }
#pragma unroll
    for (int it = 0; it < 4; ++it) {
      int idx = it * 256 + tid;
      int kk = idx >> 5, cc = (idx & 31) * 4;
      *(float4*)&Wt[kk][cc] = *(const float4*)(W + (size_t)(kt + kk) * D1 + cc);
    }
    __syncthreads();
#pragma unroll
    for (int k = 0; k < 32; ++k) {
      float4 w4 = *(const float4*)&Wt[k][tx * 4];
      float4 xa = *(const float4*)&Xs[k][ty * 8];
      float4 xb = *(const float4*)&Xs[k][ty * 8 + 4];
      float xv[8] = {xa.x, xa.y, xa.z, xa.w, xb.x, xb.y, xb.z, xb.w};
      float wv[4] = {w4.x, w4.y, w4.z, w4.w};
#pragma unroll
      for (int rr = 0; rr < 8; ++rr)
#pragma unroll
        for (int cc = 0; cc < 4; ++cc)
          acc[rr][cc] = fmaf(xv[rr], wv[cc], acc[rr][cc]);
    }
    __syncthreads();
  }

  const int h = tx >> 2;
  const int cin = (tx * 4) & 15;
  float a_sv[4], a_dv[4];
#pragma unroll
  for (int j = 0; j < 4; ++j) { a_sv[j] = aS[h * 16 + cin + j]; a_dv[j] = aD[h * 16 + cin + j]; }
#pragma unroll
  for (int rr = 0; rr < 8; ++rr) {
    int grow = row0 + ty * 8 + rr;
    if (grow < NN) {
      union { ushort4 u; __hip_bfloat16 hh[4]; } pk;
      pk.hh[0] = __float2bfloat16(acc[rr][0]);
      pk.hh[1] = __float2bfloat16(acc[rr][1]);
      pk.hh[2] = __float2bfloat16(acc[rr][2]);
      pk.hh[3] = __float2bfloat16(acc[rr][3]);
      *(ushort4*)(Yb + (size_t)grow * D1 + tx * 4) = pk.u;
      float ps = acc[rr][0] * a_sv[0] + acc[rr][1] * a_sv[1] + acc[rr][2] * a_sv[2] + acc[rr][3] * a_sv[3];
      float pd = acc[rr][0] * a_dv[0] + acc[rr][1] * a_dv[1] + acc[rr][2] * a_dv[2] + acc[rr][3] * a_dv[3];
      ps += __shfl_xor(ps, 1); pd += __shfl_xor(pd, 1);
      ps += __shfl_xor(ps, 2); pd += __shfl_xor(pd, 2);
      if ((tx & 3) == 0) { as1[grow * H1 + h] = ps; ad1[grow * H1 + h] = pd; }
    }
  }
}

// block (oct, slice): LDS histogram of slice's in-octant dsts -> hist_slice[s][d] (u16)
__device__ void hist_role(int hbid, char* smem, const int* __restrict__ ei,
                          u16* __restrict__ hs) {
  int* hl = (int*)smem;                     // OCTW ints = 25000 B
  const int oct = hbid & 7;
  const int s   = hbid >> 3;
  const int lo  = oct * OCTW;
  const int tid = threadIdx.x;
  for (int j = tid; j < OCTW; j += 256) hl[j] = 0;
  __syncthreads();
  const int4* dp = (const int4*)(ei + NE) + (size_t)s * (SLE / 4);
  for (int g = tid; g < SLE / 4; g += 256) {
    int4 v = dp[g];
    int a = v.x - lo, b = v.y - lo, c = v.z - lo, d = v.w - lo;
    if ((unsigned)a < OCTW) atomicAdd(&hl[a], 1);
    if ((unsigned)b < OCTW) atomicAdd(&hl[b], 1);
    if ((unsigned)c < OCTW) atomicAdd(&hl[c], 1);
    if ((unsigned)d < OCTW) atomicAdd(&hl[d], 1);
  }
  __syncthreads();
  u16* out = hs + (size_t)s * NN + lo;
  for (int j = tid; j < OCTW; j += 256) out[j] = (u16)hl[j];
}

__device__ void pack_role(int pbid, const int* __restrict__ ei,
                          u16* __restrict__ src16, u16* __restrict__ dst16) {
  int i = pbid * 256 + threadIdx.x;
  if (i >= NE / 4) return;
  int4 s = ((const int4*)ei)[i];
  int4 d = ((const int4*)(ei + NE))[i];
  ushort4 sp; sp.x = (u16)s.x; sp.y = (u16)s.y; sp.z = (u16)s.z; sp.w = (u16)s.w;
  ushort4 dp; dp.x = (u16)d.x; dp.y = (u16)d.y; dp.z = (u16)d.z; dp.w = (u16)d.w;
  ((ushort4*)src16)[i] = sp;
  ((ushort4*)dst16)[i] = dp;
}

__global__ __launch_bounds__(256) void k1_fused(const float* __restrict__ X,
    const float* __restrict__ W, const float* __restrict__ aS,
    const float* __restrict__ aD, __hip_bfloat16* __restrict__ Yb,
    float* __restrict__ as1, float* __restrict__ ad1,
    const int* __restrict__ ei, u16* __restrict__ hs,
    u16* __restrict__ src16, u16* __restrict__ dst16) {
  __shared__ __align__(16) char smem[25088];
  const int bid = blockIdx.x;
  if (bid < GEMM_NB) gemm1_role(bid, smem, X, W, aS, aD, Yb, as1, ad1);
  else if (bid < GEMM_NB + HIST_NB) hist_role(bid - GEMM_NB, smem, ei, hs);
  else pack_role(bid - GEMM_NB - HIST_NB, ei, src16, dst16);
}

// ==================================================================
// scans (deg[i] = 1 + sum_s hist_slice[s][i]; +1 = self loop)
// ==================================================================
__global__ __launch_bounds__(256) void scan1_k(const u16* __restrict__ hs,
                                               int* __restrict__ deg32,
                                               int* __restrict__ incl,
                                               int* __restrict__ bsum) {
  __shared__ int sm[256];
  int t = threadIdx.x, i = blockIdx.x * 256 + t;
  int v = 0;
  if (i < NN) {
    v = 1;
#pragma unroll
    for (int s = 0; s < NSL; ++s) v += (int)hs[(size_t)s * NN + i];
    deg32[i] = v;
  }
  sm[t] = v; __syncthreads();
  for (int off = 1; off < 256; off <<= 1) {
    int u = (t >= off) ? sm[t - off] : 0;
    __syncthreads();
    sm[t] += u;
    __syncthreads();
  }
  if (i < NN) incl[i] = sm[t];
  if (t == 255) bsum[blockIdx.x] = sm[255];
}

__global__ __launch_bounds__(256) void scan2_k(const int* __restrict__ bsum, int* __restrict__ boff) {
  __shared__ int sm[256];
  int t = threadIdx.x;
  int v = (t < NB1) ? bsum[t] : 0;
  sm[t] = v; __syncthreads();
  for (int off = 1; off < 256; off <<= 1) {
    int u = (t >= off) ? sm[t - off] : 0;
    __syncthreads();
    sm[t] += u;
    __syncthreads();
  }
  if (t < NB1) boff[t] = sm[t] - v;   // exclusive
}

// rowptr + self-loop placement (last slot of each segment)
__global__ __launch_bounds__(256) void scan3_k(const int* __restrict__ deg32,
                                               const int* __restrict__ incl,
                                               const int* __restrict__ boff,
                                               int* __restrict__ rowptr,
                                               u16* __restrict__ srcs) {
  int i = blockIdx.x * 256 + threadIdx.x;
  if (i >= NN) return;
  int dg = deg32[i];
  int r = incl[i] - dg + boff[i >> 8];   // exclusive scan
  rowptr[i] = r;
  srcs[r + dg - 1] = (u16)i;
  if (i == 0) rowptr[NN] = ET;
}

// ==================================================================
// deterministic scatter: zero global atomics (LDS cursors seeded from
// rowptr + prefix of per-slice histograms)
// ==================================================================
__global__ __launch_bounds__(256) void scatter_det_k(const u16* __restrict__ src16,
    const u16* __restrict__ dst16, const int* __restrict__ rowptr,
    const u16* __restrict__ hs, u16* __restrict__ srcs) {
  __shared__ int cur[OCTW];
  const int oct = blockIdx.x & 7;
  const int s   = blockIdx.x >> 3;
  const int lo  = oct * OCTW;
  const int tid = threadIdx.x;
  for (int j = tid; j < OCTW; j += 256) {
    int c = rowptr[lo + j];
    for (int sp = 0; sp < s; ++sp) c += (int)hs[(size_t)sp * NN + lo + j];
    cur[j] = c;
  }
  __syncthreads();
  const u32x4* dp = (const u32x4*)dst16 + (size_t)s * (SLE / 8);
  const u32x4* sp = (const u32x4*)src16 + (size_t)s * (SLE / 8);
  for (int g = tid; g < SLE / 8; g += 256) {
    u32x4 dv = __builtin_nontemporal_load(&dp[g]);
    u32x4 sv = __builtin_nontemporal_load(&sp[g]);
#pragma unroll
    for (int q = 0; q < 4; ++q) {
      int d0 = (int)(dv[q] & 0xffffu) - lo;
      int d1 = (int)(dv[q] >> 16) - lo;
      if ((unsigned)d0 < OCTW) srcs[atomicAdd(&cur[d0], 1)] = (u16)(sv[q] & 0xffffu);
      if ((unsigned)d1 < OCTW) srcs[atomicAdd(&cur[d1], 1)] = (u16)(sv[q] >> 16);
    }
  }
}

// ==================================================================
// fused layer-1 aggregation: 1 wave per dst, 2 ch per lane (unchanged)
// ==================================================================
__global__ __launch_bounds__(128) void agg1_k(const int* __restrict__ rowptr,
    const u16* __restrict__ srcs, const u32* __restrict__ h1u,
    const float* __restrict__ as, const float* __restrict__ ad,
    const float* __restrict__ b, float* __restrict__ z) {
  __shared__ int ssrc[2][64];
  __shared__ float wl[2][64 * 9];
  __shared__ int lens[2];
  const int w = threadIdx.x >> 6;
  const int lane = threadIdx.x & 63;
  const int d = blockIdx.x * 2 + w;
  const int h = lane >> 3;
  const int beg = rowptr[d], end = rowptr[d + 1];
  if (lane == 0) lens[w] = end - beg;
  __syncthreads();
  const int nb = (max(lens[0], lens[1]) + 63) >> 6;
  const float4 adv0 = *(const float4*)(ad + (size_t)d * H1);
  const float4 adv1 = *(const float4*)(ad + (size_t)d * H1 + 4);
  float aL0 = 0, aL1 = 0, aL2 = 0, aL3 = 0;
  float aH0 = 0, aH1 = 0, aH2 = 0, aH3 = 0;
  float dn0 = 0, dn1 = 0, dn2 = 0, dn3 = 0;
  for (int it = 0; it < nb; ++it) {
    const int base = beg + (it << 6);
    int m = end - base; m = m < 0 ? 0 : (m > 64 ? 64 : m);
    if (lane < m) {
      int s = (int)srcs[base + lane];
      ssrc[w][lane] = s;
      const float4 a0 = *(const float4*)(as + (size_t)s * H1);
      const float4 a1 = *(const float4*)(as + (size_t)s * H1 + 4);
      float* wp = &wl[w][lane * 9];
      float e;
      e = a0.x + adv0.x; e = e > 0.f ? e : 0.2f * e; wp[0] = __expf(e);
      e = a0.y + adv0.y; e = e > 0.f ? e : 0.2f * e; wp[1] = __expf(e);
      e = a0.z + adv0.z; e = e > 0.f ? e : 0.2f * e; wp[2] = __expf(e);
      e = a0.w + adv0.w; e = e > 0.f ? e : 0.2f * e; wp[3] = __expf(e);
      e = a1.x + adv1.x; e = e > 0.f ? e : 0.2f * e; wp[4] = __expf(e);
      e = a1.y + adv1.y; e = e > 0.f ? e : 0.2f * e; wp[5] = __expf(e);
      e = a1.z + adv1.z; e = e > 0.f ? e : 0.2f * e; wp[6] = __expf(e);
      e = a1.w + adv1.w; e = e > 0.f ? e : 0.2f * e; wp[7] = __expf(e);
    }
    __syncthreads();
    int j = 0;
    for (; j + 4 <= m; j += 4) {
      int s0 = ssrc[w][j], s1 = ssrc[w][j + 1], s2 = ssrc[w][j + 2], s3 = ssrc[w][j + 3];
      float w0 = wl[w][(j + 0) * 9 + h], w1 = wl[w][(j + 1) * 9 + h];
      float w2 = wl[w][(j + 2) * 9 + h], w3 = wl[w][(j + 3) * 9 + h];
      u32 v0 = h1u[(size_t)s0 * 64 + lane];
      u32 v1 = h1u[(size_t)s1 * 64 + lane];
      u32 v2 = h1u[(size_t)s2 * 64 + lane];
      u32 v3 = h1u[(size_t)s3 * 64 + lane];
      dn0 += w0; dn1 += w1; dn2 += w2; dn3 += w3;
      aL0 = fmaf(w0, __uint_as_float(v0 << 16), aL0);
      aH0 = fmaf(w0, __uint_as_float(v0 & 0xffff0000u), aH0);
      aL1 = fmaf(w1, __uint_as_float(v1 << 16), aL1);
      aH1 = fmaf(w1, __uint_as_float(v1 & 0xffff0000u), aH1);
      aL2 = fmaf(w2, __uint_as_float(v2 << 16), aL2);
      aH2 = fmaf(w2, __uint_as_float(v2 & 0xffff0000u), aH2);
      aL3 = fmaf(w3, __uint_as_float(v3 << 16), aL3);
      aH3 = fmaf(w3, __uint_as_float(v3 & 0xffff0000u), aH3);
    }
    for (; j < m; ++j) {
      int s0 = ssrc[w][j];
      float w0 = wl[w][j * 9 + h];
      u32 v0 = h1u[(size_t)s0 * 64 + lane];
      dn0 += w0;
      aL0 = fmaf(w0, __uint_as_float(v0 << 16), aL0);
      aH0 = fmaf(w0, __uint_as_float(v0 & 0xffff0000u), aH0);
    }
    __syncthreads();
  }
  float den = (dn0 + dn1) + (dn2 + dn3);
  float aL = (aL0 + aL1) + (aL2 + aL3);
  float aH = (aH0 + aH1) + (aH2 + aH3);
  float inv = 1.f / den;
  float2 bb = *(const float2*)(b + lane * 2);
  float v0 = aL * inv + bb.x;
  float v1 = aH * inv + bb.y;
  v0 = v0 > 0.f ? v0 : __expf(v0) - 1.f;
  v1 = v1 > 0.f ? v1 : __expf(v1) - 1.f;
  float2 o = {v0, v1};
  *(float2*)(z + (size_t)d * D1 + lane * 2) = o;
}

// ==================================================================
// layer 2 GEMM + fused alpha2, bf16 h2 output (unchanged)
// ==================================================================
__global__ __launch_bounds__(256) void gemm2_k(const float* __restrict__ Z,
    const float* __restrict__ W, const float* __restrict__ aS,
    const float* __restrict__ aD, __hip_bfloat16* __restrict__ Yb,
    float* __restrict__ as2, float* __restrict__ ad2) {
  __shared__ float Ws[D1][C2];
  __shared__ float Zs[16][D1 + 4];
  const int tid = threadIdx.x;
  for (int i = tid; i < D1 * C2; i += 256) Ws[i >> 4][i & 15] = W[i];
  const int rb = blockIdx.x * 16;
  {
    int r = tid >> 5, c4 = (tid & 31) * 4;
#pragma unroll
    for (int it = 0; it < 2; ++it) {
      int rr = r + it * 8;
      float4 v = *(const float4*)(Z + (size_t)(rb + rr) * D1 + c4);
      *(float4*)&Zs[rr][c4] = v;
    }
  }
  __syncthreads();
  const int r = tid >> 4, c = tid & 15;
  float a0 = 0, a1 = 0, a2 = 0, a3 = 0;
#pragma unroll
  for (int k = 0; k < D1; k += 4) {
    float4 z4 = *(const float4*)&Zs[r][k];
    a0 = fmaf(z4.x, Ws[k][c], a0);
    a1 = fmaf(z4.y, Ws[k + 1][c], a1);
    a2 = fmaf(z4.z, Ws[k + 2][c], a2);
    a3 = fmaf(z4.w, Ws[k + 3][c], a3);
  }
  float acc = (a0 + a1) + (a2 + a3);
  Yb[(size_t)(rb + r) * C2 + c] = __float2bfloat16(acc);
  float ps = acc * aS[c], pd = acc * aD[c];
  ps += __shfl_xor(ps, 1); pd += __shfl_xor(pd, 1);
  ps += __shfl_xor(ps, 2); pd += __shfl_xor(pd, 2);
  ps += __shfl_xor(ps, 4); pd += __shfl_xor(pd, 4);
  ps += __shfl_xor(ps, 8); pd += __shfl_xor(pd, 8);
  if (c == 0) { as2[rb + r] = ps; ad2[rb + r] = pd; }
}

// ==================================================================
// fused layer-2 aggregation: shfl-dedup'd weights (1 exp per edge)
// ==================================================================
__global__ __launch_bounds__(256) void agg2_k(const int* __restrict__ rowptr,
    const u16* __restrict__ srcs, const u32* __restrict__ h2u,
    const float* __restrict__ as, const float* __restrict__ ad,
    const float* __restrict__ b, float* __restrict__ outp) {
  const int wv = threadIdx.x >> 6;
  const int lane = threadIdx.x & 63;
  const int d = blockIdx.x * 4 + wv;
  const int j8 = lane >> 3, cp = lane & 7;   // edge slot, channel pair
  const int beg = rowptr[d], end = rowptr[d + 1];
  const float adv = ad[d];
  float a0 = 0, a1 = 0, den = 0;
  for (int base = beg; base < end; base += 64) {
    const int m = end - base;          // may exceed 64
    float wreg = 0.f; int sreg = 0;
    if (lane < m) {
      sreg = (int)srcs[base + lane];
      float e = as[sreg] + adv;
      e = e > 0.f ? e : 0.2f * e;
      wreg = __expf(e);
    }
    const int mm = m < 64 ? m : 64;
    const int rounds = (mm + 7) >> 3;
    for (int r = 0; r < rounds; ++r) {
      int src_lane = r * 8 + j8;
      float wgt = __shfl(wreg, src_lane);
      int s     = __shfl(sreg, src_lane);
      if (wgt > 0.f) {
        u32 v = h2u[(size_t)s * 8 + cp];
        den += wgt;
        a0 = fmaf(wgt, __uint_as_float(v << 16), a0);
        a1 = fmaf(wgt, __uint_as_float(v & 0xffff0000u), a1);
      }
    }
  }
#pragma unroll
  for (int off = 8; off < 64; off <<= 1) {
    a0 += __shfl_xor(a0, off);
    a1 += __shfl_xor(a1, off);
    den += __shfl_xor(den, off);
  }
  if (j8 == 0) {
    float inv = 1.f / den;
    float2 bb = *(const float2*)(b + cp * 2);
    float2 o = {a0 * inv + bb.x, a1 * inv + bb.y};
    *(float2*)(outp + (size_t)d * C2 + cp * 2) = o;
  }
}

extern "C" void kernel_launch(void* const* d_in, const int* in_sizes, int n_in,
                              void* d_out, int out_size, void* d_ws, size_t ws_size,
                              hipStream_t stream) {
  const float* x    = (const float*)d_in[0];
  const int*   ei   = (const int*)d_in[1];
  const float* W1   = (const float*)d_in[2];
  const float* aS1  = (const float*)d_in[3];
  const float* aD1  = (const float*)d_in[4];
  const float* b1   = (const float*)d_in[5];
  const float* W2   = (const float*)d_in[6];
  const float* aS2  = (const float*)d_in[7];
  const float* aD2  = (const float*)d_in[8];
  const float* b2   = (const float*)d_in[9];
  float* outp = (float*)d_out;

  // ---- workspace layout ----
  char* p = (char*)d_ws;
  __hip_bfloat16* h1b = (__hip_bfloat16*)p; p += (size_t)NN * D1 * 2;  // 12.8 MB
  float* z    = (float*)p; p += (size_t)NN * D1 * 4;                    // 25.6 MB
  float* as1  = (float*)p; p += (size_t)NN * H1 * 4;
  float* ad1  = (float*)p; p += (size_t)NN * H1 * 4;
  u16*   hs     = (u16*)p; p += (size_t)NSL * NN * 2;                   // 1.6 MB
  int*   deg32  = (int*)p; p += (size_t)NN * 4;
  int*   incl   = (int*)p; p += (size_t)NN * 4;
  int*   rowptr = (int*)p; p += (size_t)(NN + 1) * 4;
  int*   bsum   = (int*)p; p += 256 * 4;
  int*   boff   = (int*)p; p += 256 * 4;
  u16*   srcs   = (u16*)p; p += (size_t)ET * 2;
  u16*   src16  = (u16*)p; p += (size_t)NE * 2;
  u16*   dst16  = (u16*)p; p += (size_t)NE * 2;
  // layer-2 tensors alias h1b region (dead after agg1)
  __hip_bfloat16* h2b = h1b;                          // NN*C2 bf16
  float* as2 = (float*)(h1b + (size_t)NN * C2);
  float* ad2 = as2 + NN;

  // K1: gemm1+alpha1 | slice-hist | pack  (no memsets needed anywhere)
  k1_fused<<<GEMM_NB + HIST_NB + PACK_NB, 256, 0, stream>>>(
      x, W1, aS1, aD1, h1b, as1, ad1, ei, hs, src16, dst16);

  scan1_k<<<NB1, 256, 0, stream>>>(hs, deg32, incl, bsum);
  scan2_k<<<1, 256, 0, stream>>>(bsum, boff);
  scan3_k<<<NB1, 256, 0, stream>>>(deg32, incl, boff, rowptr, srcs);

  scatter_det_k<<<HIST_NB, 256, 0, stream>>>(src16, dst16, rowptr, hs, srcs);

  agg1_k <<<NN / 2, 128, 0, stream>>>(rowptr, srcs, (const u32*)h1b, as1, ad1, b1, z);

  gemm2_k<<<NN / 16, 256, 0, stream>>>(z, W2, aS2, aD2, h2b, as2, ad2);
  agg2_k <<<NN / 4, 256, 0, stream>>>(rowptr, srcs, (const u32*)h2b, as2, ad2, b2, outp);
}

// Round 7
// 253.720 us; speedup vs baseline: 7.6150x; 1.3260x over previous
//
#include <hip/hip_runtime.h>
#include <hip/hip_bf16.h>

#define NN 50000
#define NE 1600000
#define ET (NE + NN)   // 1,650,000 incl. self loops
#define H1 8
#define C1 16
#define D1 128
#define C2 16
#define NB1 196        // ceil(NN/256)
#define OCTW 6250      // NN/8 dsts per octant
#define NSL 64         // slices for atomic-free CSR build
#define SLE (NE / NSL) // 25,000 edges per slice

#define HIST_NB 512    // 8 octants x 64 slices
#define PACK_NB 1563   // ceil(NE/4/256)
#define SCAT_NB 512    // 8 octants x 64 slices
#define GEMM_NB 782    // ceil(50000/64)

typedef unsigned short u16;
typedef unsigned int u32;
typedef u32 u32x4 __attribute__((ext_vector_type(4)));

// ==================================================================
// K1: fused [slice-hist | pack]
// ==================================================================
// block (oct, slice): LDS histogram of slice's in-octant dsts -> hs[s][d] (u16)
__device__ void hist_role(int hbid, char* smem, const int* __restrict__ ei,
                          u16* __restrict__ hs) {
  int* hl = (int*)smem;                     // OCTW ints = 25000 B
  const int oct = hbid & 7;
  const int s   = hbid >> 3;
  const int lo  = oct * OCTW;
  const int tid = threadIdx.x;
  for (int j = tid; j < OCTW; j += 256) hl[j] = 0;
  __syncthreads();
  const int4* dp = (const int4*)(ei + NE) + (size_t)s * (SLE / 4);
  for (int g = tid; g < SLE / 4; g += 256) {
    int4 v = dp[g];
    int a = v.x - lo, b = v.y - lo, c = v.z - lo, d = v.w - lo;
    if ((unsigned)a < OCTW) atomicAdd(&hl[a], 1);
    if ((unsigned)b < OCTW) atomicAdd(&hl[b], 1);
    if ((unsigned)c < OCTW) atomicAdd(&hl[c], 1);
    if ((unsigned)d < OCTW) atomicAdd(&hl[d], 1);
  }
  __syncthreads();
  u16* out = hs + (size_t)s * NN + lo;
  for (int j = tid; j < OCTW; j += 256) out[j] = (u16)hl[j];
}

__device__ void pack_role(int pbid, const int* __restrict__ ei,
                          u16* __restrict__ src16, u16* __restrict__ dst16) {
  int i = pbid * 256 + threadIdx.x;
  if (i >= NE / 4) return;
  int4 s = ((const int4*)ei)[i];
  int4 d = ((const int4*)(ei + NE))[i];
  ushort4 sp; sp.x = (u16)s.x; sp.y = (u16)s.y; sp.z = (u16)s.z; sp.w = (u16)s.w;
  ushort4 dp; dp.x = (u16)d.x; dp.y = (u16)d.y; dp.z = (u16)d.z; dp.w = (u16)d.w;
  ((ushort4*)src16)[i] = sp;
  ((ushort4*)dst16)[i] = dp;
}

__global__ __launch_bounds__(256) void k1_fused(const int* __restrict__ ei,
    u16* __restrict__ hs, u16* __restrict__ src16, u16* __restrict__ dst16) {
  __shared__ __align__(16) char smem[25088];
  const int bid = blockIdx.x;
  if (bid < HIST_NB) hist_role(bid, smem, ei, hs);
  else pack_role(bid - HIST_NB, ei, src16, dst16);
}

// ==================================================================
// scans; scan1 also converts hs to exclusive prefix along slices (in place)
// deg[i] = 1 + sum_s hs[s][i]  (+1 = self loop)
// ==================================================================
__global__ __launch_bounds__(256) void scan1_k(u16* __restrict__ hs,
                                               int* __restrict__ deg32,
                                               int* __restrict__ incl,
                                               int* __restrict__ bsum) {
  __shared__ int sm[256];
  int t = threadIdx.x, i = blockIdx.x * 256 + t;
  int v = 0;
  if (i < NN) {
    int run = 0;
#pragma unroll
    for (int s = 0; s < NSL; ++s) {
      int c = (int)hs[(size_t)s * NN + i];
      hs[(size_t)s * NN + i] = (u16)run;   // exclusive prefix (fits: run <= deg)
      run += c;
    }
    v = run + 1;
    deg32[i] = v;
  }
  sm[t] = v; __syncthreads();
  for (int off = 1; off < 256; off <<= 1) {
    int u = (t >= off) ? sm[t - off] : 0;
    __syncthreads();
    sm[t] += u;
    __syncthreads();
  }
  if (i < NN) incl[i] = sm[t];
  if (t == 255) bsum[blockIdx.x] = sm[255];
}

__global__ __launch_bounds__(256) void scan2_k(const int* __restrict__ bsum, int* __restrict__ boff) {
  __shared__ int sm[256];
  int t = threadIdx.x;
  int v = (t < NB1) ? bsum[t] : 0;
  sm[t] = v; __syncthreads();
  for (int off = 1; off < 256; off <<= 1) {
    int u = (t >= off) ? sm[t - off] : 0;
    __syncthreads();
    sm[t] += u;
    __syncthreads();
  }
  if (t < NB1) boff[t] = sm[t] - v;   // exclusive
}

// rowptr + self-loop placement (last slot of each segment)
__global__ __launch_bounds__(256) void scan3_k(const int* __restrict__ deg32,
                                               const int* __restrict__ incl,
                                               const int* __restrict__ boff,
                                               int* __restrict__ rowptr,
                                               u16* __restrict__ srcs) {
  int i = blockIdx.x * 256 + threadIdx.x;
  if (i >= NN) return;
  int dg = deg32[i];
  int r = incl[i] - dg + boff[i >> 8];   // exclusive scan
  rowptr[i] = r;
  srcs[r + dg - 1] = (u16)i;
  if (i == 0) rowptr[NN] = ET;
}

// ==================================================================
// K2: fused [scatter | gemm1+alpha1]
//   scatter blocks first (bid&7 -> octant keeps XCD affinity);
//   gemm1 is CSR-independent, VALU-bound -> hides scatter latency.
// ==================================================================
__device__ void scatter_role(int sbid, char* smem, const u16* __restrict__ src16,
    const u16* __restrict__ dst16, const int* __restrict__ rowptr,
    const u16* __restrict__ hs, u16* __restrict__ srcs) {
  int* cur = (int*)smem;                 // OCTW ints
  const int oct = sbid & 7;
  const int s   = sbid >> 3;
  const int lo  = oct * OCTW;
  const int tid = threadIdx.x;
  const u16* seed = hs + (size_t)s * NN + lo;
  for (int j = tid; j < OCTW; j += 256)
    cur[j] = rowptr[lo + j] + (int)seed[j];
  __syncthreads();
  const u32x4* dp = (const u32x4*)dst16 + (size_t)s * (SLE / 8);
  const u32x4* sp = (const u32x4*)src16 + (size_t)s * (SLE / 8);
  for (int g = tid; g < SLE / 8; g += 256) {
    u32x4 dv = __builtin_nontemporal_load(&dp[g]);
    u32x4 sv = __builtin_nontemporal_load(&sp[g]);
#pragma unroll
    for (int q = 0; q < 4; ++q) {
      int d0 = (int)(dv[q] & 0xffffu) - lo;
      int d1 = (int)(dv[q] >> 16) - lo;
      if ((unsigned)d0 < OCTW) srcs[atomicAdd(&cur[d0], 1)] = (u16)(sv[q] & 0xffffu);
      if ((unsigned)d1 < OCTW) srcs[atomicAdd(&cur[d1], 1)] = (u16)(sv[q] >> 16);
    }
  }
}

__device__ void gemm1_role(int bid, char* smem, const float* __restrict__ X,
    const float* __restrict__ W, const float* __restrict__ aS,
    const float* __restrict__ aD, __hip_bfloat16* __restrict__ Yb,
    float* __restrict__ as1, float* __restrict__ ad1) {
  float (*Xs)[68]  = (float(*)[68])smem;            // 8704 B
  float (*Wt)[128] = (float(*)[128])(smem + 8704);  // 16384 B
  const int tid = threadIdx.x;
  const int tx = tid & 31;
  const int ty = tid >> 5;
  const int row0 = bid * 64;
  float acc[8][4] = {};

  for (int kt = 0; kt < D1; kt += 32) {
    {
      int r = tid >> 3, c4 = tid & 7;
#pragma unroll
      for (int it = 0; it < 2; ++it) {
        int row = r + it * 32;
        int grow = row0 + row; if (grow > NN - 1) grow = NN - 1;
        float4 v = *(const float4*)(X + (size_t)grow * D1 + kt + c4 * 4);
        Xs[c4 * 4 + 0][row] = v.x; Xs[c4 * 4 + 1][row] = v.y;
        Xs[c4 * 4 + 2][row] = v.z; Xs[c4 * 4 + 3][row] = v.w;
      }
    }
#pragma unroll
    for (int it = 0; it < 4; ++it) {
      int idx = it * 256 + tid;
      int kk = idx >> 5, cc = (idx & 31) * 4;
      *(float4*)&Wt[kk][cc] = *(const float4*)(W + (size_t)(kt + kk) * D1 + cc);
    }
    __syncthreads();
#pragma unroll
    for (int k = 0; k < 32; ++k) {
      float4 w4 = *(const float4*)&Wt[k][tx * 4];
      float4 xa = *(const float4*)&Xs[k][ty * 8];
      float4 xb = *(const float4*)&Xs[k][ty * 8 + 4];
      float xv[8] = {xa.x, xa.y, xa.z, xa.w, xb.x, xb.y, xb.z, xb.w};
      float wv[4] = {w4.x, w4.y, w4.z, w4.w};
#pragma unroll
      for (int rr = 0; rr < 8; ++rr)
#pragma unroll
        for (int cc = 0; cc < 4; ++cc)
          acc[rr][cc] = fmaf(xv[rr], wv[cc], acc[rr][cc]);
    }
    __syncthreads();
  }

  const int h = tx >> 2;
  const int cin = (tx * 4) & 15;
  float a_sv[4], a_dv[4];
#pragma unroll
  for (int j = 0; j < 4; ++j) { a_sv[j] = aS[h * 16 + cin + j]; a_dv[j] = aD[h * 16 + cin + j]; }
#pragma unroll
  for (int rr = 0; rr < 8; ++rr) {
    int grow = row0 + ty * 8 + rr;
    if (grow < NN) {
      union { ushort4 u; __hip_bfloat16 hh[4]; } pk;
      pk.hh[0] = __float2bfloat16(acc[rr][0]);
      pk.hh[1] = __float2bfloat16(acc[rr][1]);
      pk.hh[2] = __float2bfloat16(acc[rr][2]);
      pk.hh[3] = __float2bfloat16(acc[rr][3]);
      *(ushort4*)(Yb + (size_t)grow * D1 + tx * 4) = pk.u;
      float ps = acc[rr][0] * a_sv[0] + acc[rr][1] * a_sv[1] + acc[rr][2] * a_sv[2] + acc[rr][3] * a_sv[3];
      float pd = acc[rr][0] * a_dv[0] + acc[rr][1] * a_dv[1] + acc[rr][2] * a_dv[2] + acc[rr][3] * a_dv[3];
      ps += __shfl_xor(ps, 1); pd += __shfl_xor(pd, 1);
      ps += __shfl_xor(ps, 2); pd += __shfl_xor(pd, 2);
      if ((tx & 3) == 0) { as1[grow * H1 + h] = ps; ad1[grow * H1 + h] = pd; }
    }
  }
}

__global__ __launch_bounds__(256) void k2_fused(const u16* __restrict__ src16,
    const u16* __restrict__ dst16, const int* __restrict__ rowptr,
    const u16* __restrict__ hs, u16* __restrict__ srcs,
    const float* __restrict__ X, const float* __restrict__ W,
    const float* __restrict__ aS, const float* __restrict__ aD,
    __hip_bfloat16* __restrict__ Yb, float* __restrict__ as1, float* __restrict__ ad1) {
  __shared__ __align__(16) char smem[25088];
  const int bid = blockIdx.x;
  if (bid < SCAT_NB) scatter_role(bid, smem, src16, dst16, rowptr, hs, srcs);
  else gemm1_role(bid - SCAT_NB, smem, X, W, aS, aD, Yb, as1, ad1);
}

// ==================================================================
// fused layer-1 aggregation: 1 wave per dst, 2 ch per lane
// ==================================================================
__global__ __launch_bounds__(128) void agg1_k(const int* __restrict__ rowptr,
    const u16* __restrict__ srcs, const u32* __restrict__ h1u,
    const float* __restrict__ as, const float* __restrict__ ad,
    const float* __restrict__ b, float* __restrict__ z) {
  __shared__ int ssrc[2][64];
  __shared__ float wl[2][64 * 9];
  __shared__ int lens[2];
  const int w = threadIdx.x >> 6;
  const int lane = threadIdx.x & 63;
  const int d = blockIdx.x * 2 + w;
  const int h = lane >> 3;
  const int beg = rowptr[d], end = rowptr[d + 1];
  if (lane == 0) lens[w] = end - beg;
  __syncthreads();
  const int nb = (max(lens[0], lens[1]) + 63) >> 6;
  const float4 adv0 = *(const float4*)(ad + (size_t)d * H1);
  const float4 adv1 = *(const float4*)(ad + (size_t)d * H1 + 4);
  float aL0 = 0, aL1 = 0, aL2 = 0, aL3 = 0;
  float aH0 = 0, aH1 = 0, aH2 = 0, aH3 = 0;
  float dn0 = 0, dn1 = 0, dn2 = 0, dn3 = 0;
  for (int it = 0; it < nb; ++it) {
    const int base = beg + (it << 6);
    int m = end - base; m = m < 0 ? 0 : (m > 64 ? 64 : m);
    if (lane < m) {
      int s = (int)srcs[base + lane];
      ssrc[w][lane] = s;
      const float4 a0 = *(const float4*)(as + (size_t)s * H1);
      const float4 a1 = *(const float4*)(as + (size_t)s * H1 + 4);
      float* wp = &wl[w][lane * 9];
      float e;
      e = a0.x + adv0.x; e = e > 0.f ? e : 0.2f * e; wp[0] = __expf(e);
      e = a0.y + adv0.y; e = e > 0.f ? e : 0.2f * e; wp[1] = __expf(e);
      e = a0.z + adv0.z; e = e > 0.f ? e : 0.2f * e; wp[2] = __expf(e);
      e = a0.w + adv0.w; e = e > 0.f ? e : 0.2f * e; wp[3] = __expf(e);
      e = a1.x + adv1.x; e = e > 0.f ? e : 0.2f * e; wp[4] = __expf(e);
      e = a1.y + adv1.y; e = e > 0.f ? e : 0.2f * e; wp[5] = __expf(e);
      e = a1.z + adv1.z; e = e > 0.f ? e : 0.2f * e; wp[6] = __expf(e);
      e = a1.w + adv1.w; e = e > 0.f ? e : 0.2f * e; wp[7] = __expf(e);
    }
    __syncthreads();
    int j = 0;
    for (; j + 4 <= m; j += 4) {
      int s0 = ssrc[w][j], s1 = ssrc[w][j + 1], s2 = ssrc[w][j + 2], s3 = ssrc[w][j + 3];
      float w0 = wl[w][(j + 0) * 9 + h], w1 = wl[w][(j + 1) * 9 + h];
      float w2 = wl[w][(j + 2) * 9 + h], w3 = wl[w][(j + 3) * 9 + h];
      u32 v0 = h1u[(size_t)s0 * 64 + lane];
      u32 v1 = h1u[(size_t)s1 * 64 + lane];
      u32 v2 = h1u[(size_t)s2 * 64 + lane];
      u32 v3 = h1u[(size_t)s3 * 64 + lane];
      dn0 += w0; dn1 += w1; dn2 += w2; dn3 += w3;
      aL0 = fmaf(w0, __uint_as_float(v0 << 16), aL0);
      aH0 = fmaf(w0, __uint_as_float(v0 & 0xffff0000u), aH0);
      aL1 = fmaf(w1, __uint_as_float(v1 << 16), aL1);
      aH1 = fmaf(w1, __uint_as_float(v1 & 0xffff0000u), aH1);
      aL2 = fmaf(w2, __uint_as_float(v2 << 16), aL2);
      aH2 = fmaf(w2, __uint_as_float(v2 & 0xffff0000u), aH2);
      aL3 = fmaf(w3, __uint_as_float(v3 << 16), aL3);
      aH3 = fmaf(w3, __uint_as_float(v3 & 0xffff0000u), aH3);
    }
    for (; j < m; ++j) {
      int s0 = ssrc[w][j];
      float w0 = wl[w][j * 9 + h];
      u32 v0 = h1u[(size_t)s0 * 64 + lane];
      dn0 += w0;
      aL0 = fmaf(w0, __uint_as_float(v0 << 16), aL0);
      aH0 = fmaf(w0, __uint_as_float(v0 & 0xffff0000u), aH0);
    }
    __syncthreads();
  }
  float den = (dn0 + dn1) + (dn2 + dn3);
  float aL = (aL0 + aL1) + (aL2 + aL3);
  float aH = (aH0 + aH1) + (aH2 + aH3);
  float inv = 1.f / den;
  float2 bb = *(const float2*)(b + lane * 2);
  float v0 = aL * inv + bb.x;
  float v1 = aH * inv + bb.y;
  v0 = v0 > 0.f ? v0 : __expf(v0) - 1.f;
  v1 = v1 > 0.f ? v1 : __expf(v1) - 1.f;
  float2 o = {v0, v1};
  *(float2*)(z + (size_t)d * D1 + lane * 2) = o;
}

// ==================================================================
// layer 2 GEMM + fused alpha2, bf16 h2 output
// ==================================================================
__global__ __launch_bounds__(256) void gemm2_k(const float* __restrict__ Z,
    const float* __restrict__ W, const float* __restrict__ aS,
    const float* __restrict__ aD, __hip_bfloat16* __restrict__ Yb,
    float* __restrict__ as2, float* __restrict__ ad2) {
  __shared__ float Ws[D1][C2];
  __shared__ float Zs[16][D1 + 4];
  const int tid = threadIdx.x;
  for (int i = tid; i < D1 * C2; i += 256) Ws[i >> 4][i & 15] = W[i];
  const int rb = blockIdx.x * 16;
  {
    int r = tid >> 5, c4 = (tid & 31) * 4;
#pragma unroll
    for (int it = 0; it < 2; ++it) {
      int rr = r + it * 8;
      float4 v = *(const float4*)(Z + (size_t)(rb + rr) * D1 + c4);
      *(float4*)&Zs[rr][c4] = v;
    }
  }
  __syncthreads();
  const int r = tid >> 4, c = tid & 15;
  float a0 = 0, a1 = 0, a2 = 0, a3 = 0;
#pragma unroll
  for (int k = 0; k < D1; k += 4) {
    float4 z4 = *(const float4*)&Zs[r][k];
    a0 = fmaf(z4.x, Ws[k][c], a0);
    a1 = fmaf(z4.y, Ws[k + 1][c], a1);
    a2 = fmaf(z4.z, Ws[k + 2][c], a2);
    a3 = fmaf(z4.w, Ws[k + 3][c], a3);
  }
  float acc = (a0 + a1) + (a2 + a3);
  Yb[(size_t)(rb + r) * C2 + c] = __float2bfloat16(acc);
  float ps = acc * aS[c], pd = acc * aD[c];
  ps += __shfl_xor(ps, 1); pd += __shfl_xor(pd, 1);
  ps += __shfl_xor(ps, 2); pd += __shfl_xor(pd, 2);
  ps += __shfl_xor(ps, 4); pd += __shfl_xor(pd, 4);
  ps += __shfl_xor(ps, 8); pd += __shfl_xor(pd, 8);
  if (c == 0) { as2[rb + r] = ps; ad2[rb + r] = pd; }
}

// ==================================================================
// fused layer-2 aggregation: shfl-dedup'd weights (1 exp per edge)
// ==================================================================
__global__ __launch_bounds__(256) void agg2_k(const int* __restrict__ rowptr,
    const u16* __restrict__ srcs, const u32* __restrict__ h2u,
    const float* __restrict__ as, const float* __restrict__ ad,
    const float* __restrict__ b, float* __restrict__ outp) {
  const int wv = threadIdx.x >> 6;
  const int lane = threadIdx.x & 63;
  const int d = blockIdx.x * 4 + wv;
  const int j8 = lane >> 3, cp = lane & 7;   // edge slot, channel pair
  const int beg = rowptr[d], end = rowptr[d + 1];
  const float adv = ad[d];
  float a0 = 0, a1 = 0, den = 0;
  for (int base = beg; base < end; base += 64) {
    const int m = end - base;
    float wreg = 0.f; int sreg = 0;
    if (lane < m) {
      sreg = (int)srcs[base + lane];
      float e = as[sreg] + adv;
      e = e > 0.f ? e : 0.2f * e;
      wreg = __expf(e);
    }
    const int mm = m < 64 ? m : 64;
    const int rounds = (mm + 7) >> 3;
    for (int r = 0; r < rounds; ++r) {
      int src_lane = r * 8 + j8;
      float wgt = __shfl(wreg, src_lane);
      int s     = __shfl(sreg, src_lane);
      if (wgt > 0.f) {
        u32 v = h2u[(size_t)s * 8 + cp];
        den += wgt;
        a0 = fmaf(wgt, __uint_as_float(v << 16), a0);
        a1 = fmaf(wgt, __uint_as_float(v & 0xffff0000u), a1);
      }
    }
  }
#pragma unroll
  for (int off = 8; off < 64; off <<= 1) {
    a0 += __shfl_xor(a0, off);
    a1 += __shfl_xor(a1, off);
    den += __shfl_xor(den, off);
  }
  if (j8 == 0) {
    float inv = 1.f / den;
    float2 bb = *(const float2*)(b + cp * 2);
    float2 o = {a0 * inv + bb.x, a1 * inv + bb.y};
    *(float2*)(outp + (size_t)d * C2 + cp * 2) = o;
  }
}

extern "C" void kernel_launch(void* const* d_in, const int* in_sizes, int n_in,
                              void* d_out, int out_size, void* d_ws, size_t ws_size,
                              hipStream_t stream) {
  const float* x    = (const float*)d_in[0];
  const int*   ei   = (const int*)d_in[1];
  const float* W1   = (const float*)d_in[2];
  const float* aS1  = (const float*)d_in[3];
  const float* aD1  = (const float*)d_in[4];
  const float* b1   = (const float*)d_in[5];
  const float* W2   = (const float*)d_in[6];
  const float* aS2  = (const float*)d_in[7];
  const float* aD2  = (const float*)d_in[8];
  const float* b2   = (const float*)d_in[9];
  float* outp = (float*)d_out;

  // ---- workspace layout ----
  char* p = (char*)d_ws;
  __hip_bfloat16* h1b = (__hip_bfloat16*)p; p += (size_t)NN * D1 * 2;  // 12.8 MB
  float* z    = (float*)p; p += (size_t)NN * D1 * 4;                    // 25.6 MB
  float* as1  = (float*)p; p += (size_t)NN * H1 * 4;
  float* ad1  = (float*)p; p += (size_t)NN * H1 * 4;
  u16*   hs     = (u16*)p; p += (size_t)NSL * NN * 2;                   // 6.4 MB
  int*   deg32  = (int*)p; p += (size_t)NN * 4;
  int*   incl   = (int*)p; p += (size_t)NN * 4;
  int*   rowptr = (int*)p; p += (size_t)(NN + 1) * 4;
  int*   bsum   = (int*)p; p += 256 * 4;
  int*   boff   = (int*)p; p += 256 * 4;
  u16*   srcs   = (u16*)p; p += (size_t)ET * 2;
  u16*   src16  = (u16*)p; p += (size_t)NE * 2;
  u16*   dst16  = (u16*)p; p += (size_t)NE * 2;
  // layer-2 tensors alias h1b region (dead after agg1)
  __hip_bfloat16* h2b = h1b;                          // NN*C2 bf16
  float* as2 = (float*)(h1b + (size_t)NN * C2);
  float* ad2 = as2 + NN;

  // K1: slice-hist | pack
  k1_fused<<<HIST_NB + PACK_NB, 256, 0, stream>>>(ei, hs, src16, dst16);

  scan1_k<<<NB1, 256, 0, stream>>>(hs, deg32, incl, bsum);
  scan2_k<<<1, 256, 0, stream>>>(bsum, boff);
  scan3_k<<<NB1, 256, 0, stream>>>(deg32, incl, boff, rowptr, srcs);

  // K2: scatter | gemm1+alpha1  (scatter hides under the VALU-bound GEMM)
  k2_fused<<<SCAT_NB + GEMM_NB, 256, 0, stream>>>(
      src16, dst16, rowptr, hs, srcs, x, W1, aS1, aD1, h1b, as1, ad1);

  agg1_k <<<NN / 2, 128, 0, stream>>>(rowptr, srcs, (const u32*)h1b, as1, ad1, b1, z);

  gemm2_k<<<NN / 16, 256, 0, stream>>>(z, W2, aS2, aD2, h2b, as2, ad2);
  agg2_k <<<NN / 4, 256, 0, stream>>>(rowptr, srcs, (const u32*)h2b, as2, ad2, b2, outp);
}